// Round 1
// baseline (2021.190 us; speedup 1.0000x reference)
//
#include <hip/hip_runtime.h>
#include <math.h>

// Transformer block, fp32 baseline.
// B=2 T=2048 C=1024 H=16 DH=64 F=4096. LN is over the TIME axis (axis=1), ddof=1.
// Workspace layout (floats):
//   [0,4M)    x1 / x2 (LN outputs, reused)
//   [4M,8M)   q        -----\
//   [8M,12M)  k              |-- overlaid by h [4M,20M) after attention+proj done
//   [12M,16M) v              |
//   [16M,20M) attn_out / packed Wqkv (packed W dead once q,k,v computed)
//   [20M,24M) x_mid
//   [24M,24M+8K) LN stats (sum1,sq1,sum2,sq2)
// Total ~97 MB.

#define TDIM 2048
#define BDIM 2
#define CDIM 1024
#define HDIM 16
#define DHE  64
#define FDIM 4096
#define LNEPS 1e-5f

// ---------------- LayerNorm over T: partial stats with atomics ----------------
__global__ __launch_bounds__(256) void ln_stats(const float* __restrict__ x,
                                                float* __restrict__ sumv,
                                                float* __restrict__ sqv) {
  int c = blockIdx.x * 256 + threadIdx.x;   // column (channel)
  int b = blockIdx.y;
  int t0 = blockIdx.z * (TDIM / 16);
  const float* xp = x + ((size_t)b * TDIM + t0) * CDIM + c;
  float s = 0.f, q = 0.f;
  for (int t = 0; t < TDIM / 16; ++t) {
    float v = xp[(size_t)t * CDIM];
    s += v;
    q += v * v;
  }
  atomicAdd(&sumv[b * CDIM + c], s);
  atomicAdd(&sqv[b * CDIM + c], q);
}

__global__ __launch_bounds__(256) void ln_apply(const float* __restrict__ x,
    const float* __restrict__ sumv, const float* __restrict__ sqv,
    const float* __restrict__ gamma, const float* __restrict__ beta,
    float* __restrict__ y) {
  size_t i = (size_t)blockIdx.x * 256 + threadIdx.x;   // over B*T*C = 2^22
  int c = (int)(i & (CDIM - 1));
  int b = (int)(i >> 21);                              // T*C = 2^21
  float mean = sumv[b * CDIM + c] * (1.f / TDIM);
  float var = (sqv[b * CDIM + c] - mean * mean * (float)TDIM) * (1.f / (TDIM - 1));
  float rstd = rsqrtf(var + LNEPS);
  y[i] = gamma[c] * (x[i] - mean) * rstd + beta[c];
}

// ---------------- repack Wq/Wk/Wv: [H,C,DH] -> [C, H*DH] ----------------
__global__ __launch_bounds__(256) void pack_qkv(const float* __restrict__ Wq,
    const float* __restrict__ Wk, const float* __restrict__ Wv,
    float* __restrict__ out) {
  int i = blockIdx.x * 256 + threadIdx.x;  // over CDIM*1024
  const float* W = (blockIdx.y == 0) ? Wq : (blockIdx.y == 1) ? Wk : Wv;
  int c = i >> 10, n = i & 1023, h = n >> 6, d = n & 63;
  out[(size_t)blockIdx.y * (CDIM * 1024) + i] = W[((size_t)h * CDIM + c) * DHE + d];
}

// ---------------- fp32 tiled GEMM: C = A[M,K] @ B[K,N] (+bias)(+res)(+relu) ----------------
template<bool BIAS, bool RES, bool RELU>
__global__ __launch_bounds__(256) void gemm_f32(
    const float* __restrict__ A, const float* __restrict__ Bm,
    const float* __restrict__ bias, const float* __restrict__ res,
    float* __restrict__ Cm, int M, int N, int K) {
  __shared__ float As[16][64 + 4];   // [k][m]
  __shared__ float Bs[16][64 + 4];   // [k][n]
  int tid = threadIdx.x;
  int tx = tid & 15, ty = tid >> 4;
  int tx4 = tx * 4, ty4 = ty * 4;
  int m0 = blockIdx.y * 64, n0 = blockIdx.x * 64;
  int arow = tid >> 2, acol4 = (tid & 3) * 4;     // A tile: 64 rows x 16 k
  int brow = tid >> 4, bcol4 = (tid & 15) * 4;    // B tile: 16 rows x 64 n
  float acc[4][4] = {};
  for (int k0 = 0; k0 < K; k0 += 16) {
    float4 av = *(const float4*)(A + (size_t)(m0 + arow) * K + k0 + acol4);
    As[acol4 + 0][arow] = av.x;
    As[acol4 + 1][arow] = av.y;
    As[acol4 + 2][arow] = av.z;
    As[acol4 + 3][arow] = av.w;
    float4 bv = *(const float4*)(Bm + (size_t)(k0 + brow) * N + n0 + bcol4);
    *(float4*)&Bs[brow][bcol4] = bv;
    __syncthreads();
#pragma unroll
    for (int kk = 0; kk < 16; ++kk) {
      float4 a4 = *(const float4*)&As[kk][ty4];
      float4 b4 = *(const float4*)&Bs[kk][tx4];
      float aa[4] = {a4.x, a4.y, a4.z, a4.w};
      float bb[4] = {b4.x, b4.y, b4.z, b4.w};
#pragma unroll
      for (int i = 0; i < 4; ++i)
#pragma unroll
        for (int j = 0; j < 4; ++j)
          acc[i][j] = fmaf(aa[i], bb[j], acc[i][j]);
    }
    __syncthreads();
  }
#pragma unroll
  for (int i = 0; i < 4; ++i) {
    int m = m0 + ty4 + i;
#pragma unroll
    for (int j = 0; j < 4; ++j) {
      int n = n0 + tx4 + j;
      float v = acc[i][j];
      if (BIAS) v += bias[n];
      if (RES)  v += res[(size_t)m * N + n];
      if (RELU) v = fmaxf(v, 0.f);
      Cm[(size_t)m * N + n] = v;
    }
  }
}

// ---------------- flash-style causal attention, fp32 ----------------
// q,k,v,o in [B*T, H*DH] layout (col = h*64+d). One block = 64 q-rows of one (b,h).
__global__ __launch_bounds__(256) void attn_fwd(const float* __restrict__ q,
    const float* __restrict__ k, const float* __restrict__ v,
    float* __restrict__ o) {
  __shared__ float qs[DHE][64];   // [d][tr]
  __shared__ float ks[DHE][64];   // [d][ts]
  __shared__ float vs[64][DHE];   // [ts][d]
  __shared__ float ps[64][64];    // [ts][tr]
  int bh = blockIdx.y;
  int b = bh >> 4, h = bh & 15;
  int bx = blockIdx.x;
  int tq0 = bx * 64;
  int tid = threadIdx.x;
  int tx = tid & 15, ty = tid >> 4;
  int tx4 = tx * 4, ty4 = ty * 4;

  {  // stage q tile transposed: qs[d][t]
    int trow = tid >> 4;
    int d4 = (tid & 15) * 4;
#pragma unroll
    for (int r = 0; r < 4; ++r) {
      int t = trow + r * 16;
      float4 qv = *(const float4*)(q + ((size_t)(b * TDIM) + tq0 + t) * CDIM + h * DHE + d4);
      qs[d4 + 0][t] = qv.x; qs[d4 + 1][t] = qv.y;
      qs[d4 + 2][t] = qv.z; qs[d4 + 3][t] = qv.w;
    }
  }

  float m_i[4], l_i[4], Oa[4][4];
#pragma unroll
  for (int i = 0; i < 4; ++i) {
    m_i[i] = -INFINITY; l_i[i] = 0.f;
#pragma unroll
    for (int j = 0; j < 4; ++j) Oa[i][j] = 0.f;
  }

  for (int t2 = 0; t2 <= bx; ++t2) {
    __syncthreads();  // protect ks/vs/ps from previous iteration readers
    {  // stage k (transposed) and v (natural)
      int trow = tid >> 4;
      int d4 = (tid & 15) * 4;
#pragma unroll
      for (int r = 0; r < 4; ++r) {
        int t = trow + r * 16;
        size_t base = ((size_t)(b * TDIM) + t2 * 64 + t) * CDIM + h * DHE + d4;
        float4 kv = *(const float4*)(k + base);
        ks[d4 + 0][t] = kv.x; ks[d4 + 1][t] = kv.y;
        ks[d4 + 2][t] = kv.z; ks[d4 + 3][t] = kv.w;
        float4 vv = *(const float4*)(v + base);
        *(float4*)&vs[t][d4] = vv;
      }
    }
    __syncthreads();

    // S = q @ k^T  (4x4 per thread)
    float s[4][4] = {};
#pragma unroll 8
    for (int dk = 0; dk < DHE; ++dk) {
      float4 a4 = *(const float4*)&qs[dk][ty4];
      float4 b4 = *(const float4*)&ks[dk][tx4];
      float aa[4] = {a4.x, a4.y, a4.z, a4.w};
      float bb[4] = {b4.x, b4.y, b4.z, b4.w};
#pragma unroll
      for (int i = 0; i < 4; ++i)
#pragma unroll
        for (int j = 0; j < 4; ++j)
          s[i][j] = fmaf(aa[i], bb[j], s[i][j]);
    }
    const float scale = 0.03125f;  // C^-0.5 = 1/32 (faithful to source: full C, not DH)
    bool diag = (t2 == bx);
#pragma unroll
    for (int i = 0; i < 4; ++i)
#pragma unroll
      for (int j = 0; j < 4; ++j) {
        float val = s[i][j] * scale;
        if (diag && (tx4 + j > ty4 + i)) val = -INFINITY;
        s[i][j] = val;
      }

    // online softmax: row reductions across tx (16 lanes per row-group)
    float alpha[4];
#pragma unroll
    for (int i = 0; i < 4; ++i) {
      float rm = fmaxf(fmaxf(s[i][0], s[i][1]), fmaxf(s[i][2], s[i][3]));
#pragma unroll
      for (int off = 1; off < 16; off <<= 1) rm = fmaxf(rm, __shfl_xor(rm, off));
      float nm = fmaxf(m_i[i], rm);
      float sum = 0.f;
#pragma unroll
      for (int j = 0; j < 4; ++j) {
        float p = expf(s[i][j] - nm);   // exp(-inf)=0 handles mask
        s[i][j] = p;
        sum += p;
      }
#pragma unroll
      for (int off = 1; off < 16; off <<= 1) sum += __shfl_xor(sum, off);
      alpha[i] = expf(m_i[i] - nm);
      m_i[i] = nm;
      l_i[i] = l_i[i] * alpha[i] + sum;
#pragma unroll
      for (int j = 0; j < 4; ++j) ps[tx4 + j][ty4 + i] = s[i][j];  // transposed for PV
    }
    __syncthreads();

    // O = O*alpha + P @ V
#pragma unroll
    for (int i = 0; i < 4; ++i)
#pragma unroll
      for (int j = 0; j < 4; ++j) Oa[i][j] *= alpha[i];
#pragma unroll 8
    for (int ts = 0; ts < 64; ++ts) {
      float4 p4 = *(const float4*)&ps[ts][ty4];
      float4 v4 = *(const float4*)&vs[ts][tx4];
      float pp[4] = {p4.x, p4.y, p4.z, p4.w};
      float vv[4] = {v4.x, v4.y, v4.z, v4.w};
#pragma unroll
      for (int i = 0; i < 4; ++i)
#pragma unroll
        for (int j = 0; j < 4; ++j)
          Oa[i][j] = fmaf(pp[i], vv[j], Oa[i][j]);
    }
  }

#pragma unroll
  for (int i = 0; i < 4; ++i) {
    float inv = 1.f / l_i[i];
    size_t row = (size_t)(b * TDIM) + tq0 + ty4 + i;
#pragma unroll
    for (int j = 0; j < 4; ++j)
      o[row * CDIM + h * DHE + tx4 + j] = Oa[i][j] * inv;
  }
}

// ---------------- launch ----------------
extern "C" void kernel_launch(void* const* d_in, const int* in_sizes, int n_in,
                              void* d_out, int out_size, void* d_ws, size_t ws_size,
                              hipStream_t stream) {
  (void)in_sizes; (void)n_in; (void)out_size; (void)ws_size;
  const float* x   = (const float*)d_in[0];
  const float* Wq  = (const float*)d_in[1];
  const float* Wk  = (const float*)d_in[2];
  const float* Wv  = (const float*)d_in[3];
  const float* Wo  = (const float*)d_in[4];
  const float* bo  = (const float*)d_in[5];
  const float* W1  = (const float*)d_in[6];
  const float* b1  = (const float*)d_in[7];
  const float* W2  = (const float*)d_in[8];
  const float* b2  = (const float*)d_in[9];
  const float* g1  = (const float*)d_in[10];
  const float* be1 = (const float*)d_in[11];
  const float* g2  = (const float*)d_in[12];
  const float* be2 = (const float*)d_in[13];
  float* out = (float*)d_out;

  float* ws   = (float*)d_ws;
  const size_t M1 = 1024 * 1024;
  float* x1    = ws;                 // 4M floats (x1, later x2)
  float* qf    = ws + 4  * M1;
  float* kf    = ws + 8  * M1;
  float* vf    = ws + 12 * M1;
  float* ebuf  = ws + 16 * M1;       // packed Wqkv first, then attn output
  float* xmid  = ws + 20 * M1;
  float* stats = ws + 24 * M1;       // sum1, sq1, sum2, sq2 (2048 each)
  float* hbuf  = qf;                 // h [4096,4096] overlays q,k,v,ebuf (16M floats)

  float* sum1 = stats,        *sq1 = stats + 2048;
  float* sum2 = stats + 4096, *sq2 = stats + 6144;

  hipMemsetAsync(stats, 0, 4 * 2048 * sizeof(float), stream);
  pack_qkv<<<dim3(4096, 3), 256, 0, stream>>>(Wq, Wk, Wv, ebuf);

  // LN1 (over T) -> x1
  ln_stats<<<dim3(CDIM / 256, BDIM, 16), 256, 0, stream>>>(x, sum1, sq1);
  ln_apply<<<dim3((BDIM * TDIM * CDIM) / 256), 256, 0, stream>>>(x, sum1, sq1, g1, be1, x1);

  // QKV projections: [4096,1024] @ [1024,1024]
  gemm_f32<false, false, false><<<dim3(16, 64), 256, 0, stream>>>(x1, ebuf,            nullptr, nullptr, qf, 4096, 1024, 1024);
  gemm_f32<false, false, false><<<dim3(16, 64), 256, 0, stream>>>(x1, ebuf + 1 * M1,   nullptr, nullptr, kf, 4096, 1024, 1024);
  gemm_f32<false, false, false><<<dim3(16, 64), 256, 0, stream>>>(x1, ebuf + 2 * M1,   nullptr, nullptr, vf, 4096, 1024, 1024);

  // causal attention -> ebuf (overwrites packed W, no longer needed)
  attn_fwd<<<dim3(TDIM / 64, BDIM * HDIM), 256, 0, stream>>>(qf, kf, vf, ebuf);

  // output projection + residual: x_mid = x + attn @ Wo + bo
  gemm_f32<true, true, false><<<dim3(16, 64), 256, 0, stream>>>(ebuf, Wo, bo, x, xmid, 4096, 1024, 1024);

  // LN2 (over T) -> x2 (reuse x1 buffer)
  ln_stats<<<dim3(CDIM / 256, BDIM, 16), 256, 0, stream>>>(xmid, sum2, sq2);
  ln_apply<<<dim3((BDIM * TDIM * CDIM) / 256), 256, 0, stream>>>(xmid, sum2, sq2, g2, be2, x1);

  // FFN: h = relu(x2 @ W1 + b1); out = x_mid + h @ W2 + b2
  gemm_f32<true, false, true ><<<dim3(64, 64), 256, 0, stream>>>(x1, W1, b1, nullptr, hbuf, 4096, 4096, 1024);
  gemm_f32<true, true,  false><<<dim3(16, 64), 256, 0, stream>>>(hbuf, W2, b2, xmid, out, 4096, 1024, 4096);
}

// Round 2
// 897.210 us; speedup vs baseline: 2.2528x; 2.2528x over previous
//
#include <hip/hip_runtime.h>
#include <math.h>

// Transformer block. bf16 MFMA GEMMs (m97-style 128x128 tile), fp32 flash attention.
// B=2 T=2048 C=1024 H=16 DH=64 F=4096. LN over TIME axis (ddof=1).
//
// Workspace (byte offsets, total 96MB + 32KB — same footprint as fp32 baseline):
//   [0,48M)    qkv fp32 [4096][3072]          (dead after attn)
//     [0,8M)     x2b bf16 (reuse, after attn) [4096][1024]
//     [8M,40M)   hb  bf16 (reuse, after attn) [4096][4096]
//   [48M,64M)  xmid fp32 [4096][1024]
//   [64M,72M)  x1b bf16, then attnb bf16 [4096][1024]
//   [72M,78M)  Wqkvb bf16 [3072][1024]  (B^T layout: [N][K])
//   [78M,80M)  Wob  bf16 [1024][1024]   ([N][K])
//   [80M,88M)  W1b  bf16 [4096][1024]   ([N][K])
//   [88M,96M)  W2b  bf16 [1024][4096]   ([N][K])
//   [96M,96M+32K) LN stats

#define TDIM 2048
#define BDIM 2
#define CDIM 1024
#define HDIM 16
#define DHE  64
#define LNEPS 1e-5f

typedef float f32x4 __attribute__((ext_vector_type(4)));
typedef __bf16 bf16x8 __attribute__((ext_vector_type(8)));

__device__ __forceinline__ void gld_lds16(const __bf16* g, __bf16* l) {
  __builtin_amdgcn_global_load_lds(
      (const __attribute__((address_space(1))) void*)g,
      (__attribute__((address_space(3))) void*)l, 16, 0, 0);
}

// ---------------- LayerNorm over T ----------------
__global__ __launch_bounds__(256) void ln_stats(const float* __restrict__ x,
                                                float* __restrict__ sumv,
                                                float* __restrict__ sqv) {
  int c = blockIdx.x * 256 + threadIdx.x;
  int b = blockIdx.y;
  int t0 = blockIdx.z * (TDIM / 16);
  const float* xp = x + ((size_t)b * TDIM + t0) * CDIM + c;
  float s = 0.f, q = 0.f;
  for (int t = 0; t < TDIM / 16; ++t) {
    float v = xp[(size_t)t * CDIM];
    s += v;
    q += v * v;
  }
  atomicAdd(&sumv[b * CDIM + c], s);
  atomicAdd(&sqv[b * CDIM + c], q);
}

__global__ __launch_bounds__(256) void ln_apply(const float* __restrict__ x,
    const float* __restrict__ sumv, const float* __restrict__ sqv,
    const float* __restrict__ gamma, const float* __restrict__ beta,
    __bf16* __restrict__ y) {
  size_t i = (size_t)blockIdx.x * 256 + threadIdx.x;
  int c = (int)(i & (CDIM - 1));
  int b = (int)(i >> 21);
  float mean = sumv[b * CDIM + c] * (1.f / TDIM);
  float var = (sqv[b * CDIM + c] - mean * mean * (float)TDIM) * (1.f / (TDIM - 1));
  float rstd = rsqrtf(var + LNEPS);
  y[i] = (__bf16)(gamma[c] * (x[i] - mean) * rstd + beta[c]);
}

// ---------------- weight repacks (transposed, bf16, [N][K]) ----------------
// Wq/Wk/Wv [H,C,DH] -> Wqkvb [3072][1024]: row n = mat*1024 + h*64 + d, col = c
__global__ __launch_bounds__(256) void pack_qkvT(const float* __restrict__ Wq,
    const float* __restrict__ Wk, const float* __restrict__ Wv,
    __bf16* __restrict__ out) {
  __shared__ float tile[32][33];
  int mat = blockIdx.z >> 4, h = blockIdx.z & 15;
  const float* W = (mat == 0) ? Wq : (mat == 1) ? Wk : Wv;
  int c0 = blockIdx.x * 32, d0 = blockIdx.y * 32;
  int tx = threadIdx.x & 31, ty = threadIdx.x >> 5;
#pragma unroll
  for (int i = 0; i < 4; ++i)
    tile[ty + i * 8][tx] = W[((size_t)h * CDIM + c0 + ty + i * 8) * DHE + d0 + tx];
  __syncthreads();
#pragma unroll
  for (int i = 0; i < 4; ++i) {
    int n = mat * 1024 + h * 64 + d0 + ty + i * 8;
    out[(size_t)n * CDIM + c0 + tx] = (__bf16)tile[tx][ty + i * 8];
  }
}

// generic: in [R][Cc] f32 -> out [Cc][R] bf16
__global__ __launch_bounds__(256) void transp_bf16(const float* __restrict__ in,
    __bf16* __restrict__ out, int R, int Cc) {
  __shared__ float tile[32][33];
  int c0 = blockIdx.x * 32, r0 = blockIdx.y * 32;
  int tx = threadIdx.x & 31, ty = threadIdx.x >> 5;
#pragma unroll
  for (int i = 0; i < 4; ++i)
    tile[ty + i * 8][tx] = in[(size_t)(r0 + ty + i * 8) * Cc + c0 + tx];
  __syncthreads();
#pragma unroll
  for (int i = 0; i < 4; ++i)
    out[(size_t)(c0 + ty + i * 8) * R + r0 + tx] = (__bf16)tile[tx][ty + i * 8];
}

// ---------------- bf16 MFMA GEMM: C[M,N] = A[M,K] @ Bt[N,K]^T ----------------
// 128x128 tile, BK=32, 4 waves (2x2), 4x4 16x16x32 frags per wave.
template<bool BIAS, bool RES, bool RELU, bool OUTBF>
__global__ __launch_bounds__(256) void gemm_bf16(
    const __bf16* __restrict__ Ag, const __bf16* __restrict__ Bg,
    const float* __restrict__ bias, const float* __restrict__ res,
    void* __restrict__ Cm, int M, int N, int K) {
  __shared__ __bf16 As[128 * 32];
  __shared__ __bf16 Bs[128 * 32];
  int tid = threadIdx.x;
  int lane = tid & 63, wid = tid >> 6;
  int wr = wid >> 1, wc = wid & 1;
  int m0 = blockIdx.y * 128, n0 = blockIdx.x * 128;
  int srow = tid >> 2, scol = (tid & 3) * 8;   // staging: 4 lanes/row, 16B each
  int l15 = lane & 15, k8 = (lane >> 4) * 8;

  f32x4 acc[4][4];
#pragma unroll
  for (int m = 0; m < 4; ++m)
#pragma unroll
    for (int n = 0; n < 4; ++n) acc[m][n] = (f32x4){0.f, 0.f, 0.f, 0.f};

  for (int k0 = 0; k0 < K; k0 += 32) {
    __syncthreads();   // previous iteration's LDS reads complete
    gld_lds16(Ag + (size_t)(m0 + srow) * K + k0 + scol,       As + tid * 8);
    gld_lds16(Ag + (size_t)(m0 + 64 + srow) * K + k0 + scol,  As + 2048 + tid * 8);
    gld_lds16(Bg + (size_t)(n0 + srow) * K + k0 + scol,       Bs + tid * 8);
    gld_lds16(Bg + (size_t)(n0 + 64 + srow) * K + k0 + scol,  Bs + 2048 + tid * 8);
    __syncthreads();   // staging complete (vmcnt drained by barrier)

    bf16x8 af[4], bf[4];
#pragma unroll
    for (int m = 0; m < 4; ++m)
      af[m] = *(const bf16x8*)(As + (wr * 64 + m * 16 + l15) * 32 + k8);
#pragma unroll
    for (int n = 0; n < 4; ++n)
      bf[n] = *(const bf16x8*)(Bs + (wc * 64 + n * 16 + l15) * 32 + k8);
#pragma unroll
    for (int m = 0; m < 4; ++m)
#pragma unroll
      for (int n = 0; n < 4; ++n)
        acc[m][n] = __builtin_amdgcn_mfma_f32_16x16x32_bf16(af[m], bf[n], acc[m][n], 0, 0, 0);
  }

  int rbase = (lane >> 4) * 4;
#pragma unroll
  for (int m = 0; m < 4; ++m) {
    int row = m0 + wr * 64 + m * 16 + rbase;
#pragma unroll
    for (int n = 0; n < 4; ++n) {
      int col = n0 + wc * 64 + n * 16 + l15;
#pragma unroll
      for (int j = 0; j < 4; ++j) {
        float v = acc[m][n][j];
        size_t off = (size_t)(row + j) * N + col;
        if (BIAS) v += bias[col];
        if (RES)  v += res[off];
        if (RELU) v = fmaxf(v, 0.f);
        if (OUTBF) ((__bf16*)Cm)[off] = (__bf16)v;
        else       ((float*)Cm)[off] = v;
      }
    }
  }
}

// ---------------- flash-style causal attention, fp32 ----------------
// qkv fp32 [B*T][3072]: q at col h*64, k at 1024+h*64, v at 2048+h*64.
// out bf16 [B*T][1024].
#define QKVS 3072
__global__ __launch_bounds__(256) void attn_fwd(const float* __restrict__ qkv,
    __bf16* __restrict__ o) {
  __shared__ float qs[DHE][64];
  __shared__ float ks[DHE][64];
  __shared__ float vs[64][DHE];
  __shared__ float ps[64][64];
  int bh = blockIdx.y;
  int b = bh >> 4, h = bh & 15;
  int bx = blockIdx.x;
  int tq0 = bx * 64;
  int tid = threadIdx.x;
  int tx = tid & 15, ty = tid >> 4;
  int tx4 = tx * 4, ty4 = ty * 4;

  {
    int trow = tid >> 4;
    int d4 = (tid & 15) * 4;
#pragma unroll
    for (int r = 0; r < 4; ++r) {
      int t = trow + r * 16;
      float4 qv = *(const float4*)(qkv + ((size_t)(b * TDIM) + tq0 + t) * QKVS + h * DHE + d4);
      qs[d4 + 0][t] = qv.x; qs[d4 + 1][t] = qv.y;
      qs[d4 + 2][t] = qv.z; qs[d4 + 3][t] = qv.w;
    }
  }

  float m_i[4], l_i[4], Oa[4][4];
#pragma unroll
  for (int i = 0; i < 4; ++i) {
    m_i[i] = -INFINITY; l_i[i] = 0.f;
#pragma unroll
    for (int j = 0; j < 4; ++j) Oa[i][j] = 0.f;
  }

  for (int t2 = 0; t2 <= bx; ++t2) {
    __syncthreads();
    {
      int trow = tid >> 4;
      int d4 = (tid & 15) * 4;
#pragma unroll
      for (int r = 0; r < 4; ++r) {
        int t = trow + r * 16;
        size_t base = ((size_t)(b * TDIM) + t2 * 64 + t) * QKVS + h * DHE + d4;
        float4 kv = *(const float4*)(qkv + 1024 + base);
        ks[d4 + 0][t] = kv.x; ks[d4 + 1][t] = kv.y;
        ks[d4 + 2][t] = kv.z; ks[d4 + 3][t] = kv.w;
        float4 vv = *(const float4*)(qkv + 2048 + base);
        *(float4*)&vs[t][d4] = vv;
      }
    }
    __syncthreads();

    float s[4][4] = {};
#pragma unroll 8
    for (int dk = 0; dk < DHE; ++dk) {
      float4 a4 = *(const float4*)&qs[dk][ty4];
      float4 b4 = *(const float4*)&ks[dk][tx4];
      float aa[4] = {a4.x, a4.y, a4.z, a4.w};
      float bb[4] = {b4.x, b4.y, b4.z, b4.w};
#pragma unroll
      for (int i = 0; i < 4; ++i)
#pragma unroll
        for (int j = 0; j < 4; ++j)
          s[i][j] = fmaf(aa[i], bb[j], s[i][j]);
    }
    const float scale = 0.03125f;
    bool diag = (t2 == bx);
#pragma unroll
    for (int i = 0; i < 4; ++i)
#pragma unroll
      for (int j = 0; j < 4; ++j) {
        float val = s[i][j] * scale;
        if (diag && (tx4 + j > ty4 + i)) val = -INFINITY;
        s[i][j] = val;
      }

    float alpha[4];
#pragma unroll
    for (int i = 0; i < 4; ++i) {
      float rm = fmaxf(fmaxf(s[i][0], s[i][1]), fmaxf(s[i][2], s[i][3]));
#pragma unroll
      for (int off = 1; off < 16; off <<= 1) rm = fmaxf(rm, __shfl_xor(rm, off));
      float nm = fmaxf(m_i[i], rm);
      float sum = 0.f;
#pragma unroll
      for (int j = 0; j < 4; ++j) {
        float p = expf(s[i][j] - nm);
        s[i][j] = p;
        sum += p;
      }
#pragma unroll
      for (int off = 1; off < 16; off <<= 1) sum += __shfl_xor(sum, off);
      alpha[i] = expf(m_i[i] - nm);
      m_i[i] = nm;
      l_i[i] = l_i[i] * alpha[i] + sum;
#pragma unroll
      for (int j = 0; j < 4; ++j) ps[tx4 + j][ty4 + i] = s[i][j];
    }
    __syncthreads();

#pragma unroll
    for (int i = 0; i < 4; ++i)
#pragma unroll
      for (int j = 0; j < 4; ++j) Oa[i][j] *= alpha[i];
#pragma unroll 8
    for (int ts = 0; ts < 64; ++ts) {
      float4 p4 = *(const float4*)&ps[ts][ty4];
      float4 v4 = *(const float4*)&vs[ts][tx4];
      float pp[4] = {p4.x, p4.y, p4.z, p4.w};
      float vv[4] = {v4.x, v4.y, v4.z, v4.w};
#pragma unroll
      for (int i = 0; i < 4; ++i)
#pragma unroll
        for (int j = 0; j < 4; ++j)
          Oa[i][j] = fmaf(pp[i], vv[j], Oa[i][j]);
    }
  }

#pragma unroll
  for (int i = 0; i < 4; ++i) {
    float inv = 1.f / l_i[i];
    size_t row = (size_t)(b * TDIM) + tq0 + ty4 + i;
#pragma unroll
    for (int j = 0; j < 4; ++j)
      o[row * CDIM + h * DHE + tx4 + j] = (__bf16)(Oa[i][j] * inv);
  }
}

// ---------------- launch ----------------
extern "C" void kernel_launch(void* const* d_in, const int* in_sizes, int n_in,
                              void* d_out, int out_size, void* d_ws, size_t ws_size,
                              hipStream_t stream) {
  (void)in_sizes; (void)n_in; (void)out_size; (void)ws_size;
  const float* x   = (const float*)d_in[0];
  const float* Wq  = (const float*)d_in[1];
  const float* Wk  = (const float*)d_in[2];
  const float* Wv  = (const float*)d_in[3];
  const float* Wo  = (const float*)d_in[4];
  const float* bo  = (const float*)d_in[5];
  const float* W1  = (const float*)d_in[6];
  const float* b1  = (const float*)d_in[7];
  const float* W2  = (const float*)d_in[8];
  const float* b2  = (const float*)d_in[9];
  const float* g1  = (const float*)d_in[10];
  const float* be1 = (const float*)d_in[11];
  const float* g2  = (const float*)d_in[12];
  const float* be2 = (const float*)d_in[13];
  float* out = (float*)d_out;

  char* wsb = (char*)d_ws;
  const size_t MB = 1024 * 1024;
  float*  qkv   = (float*) (wsb + 0);
  __bf16* x2b   = (__bf16*)(wsb + 0);
  __bf16* hb    = (__bf16*)(wsb + 8  * MB);
  float*  xmid  = (float*) (wsb + 48 * MB);
  __bf16* x1b   = (__bf16*)(wsb + 64 * MB);
  __bf16* attnb = (__bf16*)(wsb + 64 * MB);
  __bf16* Wqkvb = (__bf16*)(wsb + 72 * MB);
  __bf16* Wob   = (__bf16*)(wsb + 78 * MB);
  __bf16* W1b   = (__bf16*)(wsb + 80 * MB);
  __bf16* W2b   = (__bf16*)(wsb + 88 * MB);
  float*  stats = (float*) (wsb + 96 * MB);
  float* sum1 = stats,        *sq1 = stats + 2048;
  float* sum2 = stats + 4096, *sq2 = stats + 6144;

  hipMemsetAsync(stats, 0, 4 * 2048 * sizeof(float), stream);

  // weight repacks (bf16, [N][K])
  pack_qkvT<<<dim3(32, 2, 48), 256, 0, stream>>>(Wq, Wk, Wv, Wqkvb);
  transp_bf16<<<dim3(32, 32),  256, 0, stream>>>(Wo, Wob, 1024, 1024);
  transp_bf16<<<dim3(128, 32), 256, 0, stream>>>(W1, W1b, 1024, 4096);
  transp_bf16<<<dim3(32, 128), 256, 0, stream>>>(W2, W2b, 4096, 1024);

  // LN1 -> x1b (bf16)
  ln_stats<<<dim3(CDIM / 256, BDIM, 16), 256, 0, stream>>>(x, sum1, sq1);
  ln_apply<<<dim3((BDIM * TDIM * CDIM) / 256), 256, 0, stream>>>(x, sum1, sq1, g1, be1, x1b);

  // fused QKV projection: qkv[4096,3072] = x1b @ Wqkvb^T (fp32 out)
  gemm_bf16<false, false, false, false><<<dim3(24, 32), 256, 0, stream>>>(
      x1b, Wqkvb, nullptr, nullptr, qkv, 4096, 3072, 1024);

  // causal attention -> attnb (bf16)
  attn_fwd<<<dim3(TDIM / 64, BDIM * HDIM), 256, 0, stream>>>(qkv, attnb);

  // output projection + residual: xmid = x + attnb @ Wob^T + bo (fp32)
  gemm_bf16<true, true, false, false><<<dim3(8, 32), 256, 0, stream>>>(
      attnb, Wob, bo, x, xmid, 4096, 1024, 1024);

  // LN2 -> x2b (bf16)
  ln_stats<<<dim3(CDIM / 256, BDIM, 16), 256, 0, stream>>>(xmid, sum2, sq2);
  ln_apply<<<dim3((BDIM * TDIM * CDIM) / 256), 256, 0, stream>>>(xmid, sum2, sq2, g2, be2, x2b);

  // FFN: hb = relu(x2b @ W1b^T + b1) (bf16); out = xmid + hb @ W2b^T + b2 (fp32)
  gemm_bf16<true, false, true, true><<<dim3(32, 32), 256, 0, stream>>>(
      x2b, W1b, b1, nullptr, hb, 4096, 4096, 1024);
  gemm_bf16<true, true, false, false><<<dim3(8, 32), 256, 0, stream>>>(
      hb, W2b, b2, xmid, out, 4096, 1024, 4096);
}

// Round 3
// 386.215 us; speedup vs baseline: 5.2333x; 2.3231x over previous
//
#include <hip/hip_runtime.h>
#include <math.h>

// Transformer block. bf16 MFMA GEMMs (128x128 tile) + bf16 MFMA flash attention.
// B=2 T=2048 C=1024 H=16 DH=64 F=4096. LN over TIME axis (ddof=1).
//
// Workspace (byte offsets):
//   [0,6M)     Wqkvb bf16 [3072][1024]  ([N][K])
//   [6M,8M)    Wob   bf16 [1024][1024]
//   [8M,16M)   W1b   bf16 [4096][1024]
//   [16M,24M)  W2b   bf16 [1024][4096]
//   [24M,48M)  qkvb  bf16 [4096][3072]   \ overlaid by hb bf16 [4096][4096] ([24M,56M))
//   [48M,56M)  vt    bf16 [2048][2048]   /   (both dead before FFN)
//   [56M,64M)  x1b bf16, then attnb bf16 [4096][1024]
//   [64M,80M)  xmid fp32 [4096][1024]
//   [80M,88M)  x2b bf16
//   [88M,88M+32K) LN stats

#define TDIM 2048
#define BDIM 2
#define CDIM 1024
#define HDIM 16
#define DHE  64
#define QKVS 3072
#define LNEPS 1e-5f

typedef float f32x4 __attribute__((ext_vector_type(4)));
typedef __bf16 bf16x8 __attribute__((ext_vector_type(8)));

__device__ __forceinline__ void gld_lds16(const __bf16* g, __bf16* l) {
  __builtin_amdgcn_global_load_lds(
      (const __attribute__((address_space(1))) void*)g,
      (__attribute__((address_space(3))) void*)l, 16, 0, 0);
}

// ---------------- LayerNorm over T ----------------
__global__ __launch_bounds__(256) void ln_stats(const float* __restrict__ x,
                                                float* __restrict__ sumv,
                                                float* __restrict__ sqv) {
  int c = blockIdx.x * 256 + threadIdx.x;
  int b = blockIdx.y;
  int t0 = blockIdx.z * (TDIM / 16);
  const float* xp = x + ((size_t)b * TDIM + t0) * CDIM + c;
  float s = 0.f, q = 0.f;
  for (int t = 0; t < TDIM / 16; ++t) {
    float v = xp[(size_t)t * CDIM];
    s += v;
    q += v * v;
  }
  atomicAdd(&sumv[b * CDIM + c], s);
  atomicAdd(&sqv[b * CDIM + c], q);
}

__global__ __launch_bounds__(256) void ln_apply(const float* __restrict__ x,
    const float* __restrict__ sumv, const float* __restrict__ sqv,
    const float* __restrict__ gamma, const float* __restrict__ beta,
    __bf16* __restrict__ y) {
  size_t i = (size_t)blockIdx.x * 256 + threadIdx.x;
  int c = (int)(i & (CDIM - 1));
  int b = (int)(i >> 21);
  float mean = sumv[b * CDIM + c] * (1.f / TDIM);
  float var = (sqv[b * CDIM + c] - mean * mean * (float)TDIM) * (1.f / (TDIM - 1));
  float rstd = rsqrtf(var + LNEPS);
  y[i] = (__bf16)(gamma[c] * (x[i] - mean) * rstd + beta[c]);
}

// ---------------- weight repacks (transposed, bf16, [N][K]) ----------------
__global__ __launch_bounds__(256) void pack_qkvT(const float* __restrict__ Wq,
    const float* __restrict__ Wk, const float* __restrict__ Wv,
    __bf16* __restrict__ out) {
  __shared__ float tile[32][33];
  int mat = blockIdx.z >> 4, h = blockIdx.z & 15;
  const float* W = (mat == 0) ? Wq : (mat == 1) ? Wk : Wv;
  int c0 = blockIdx.x * 32, d0 = blockIdx.y * 32;
  int tx = threadIdx.x & 31, ty = threadIdx.x >> 5;
#pragma unroll
  for (int i = 0; i < 4; ++i)
    tile[ty + i * 8][tx] = W[((size_t)h * CDIM + c0 + ty + i * 8) * DHE + d0 + tx];
  __syncthreads();
#pragma unroll
  for (int i = 0; i < 4; ++i) {
    int n = mat * 1024 + h * 64 + d0 + ty + i * 8;
    out[(size_t)n * CDIM + c0 + tx] = (__bf16)tile[tx][ty + i * 8];
  }
}

__global__ __launch_bounds__(256) void transp_bf16(const float* __restrict__ in,
    __bf16* __restrict__ out, int R, int Cc) {
  __shared__ float tile[32][33];
  int c0 = blockIdx.x * 32, r0 = blockIdx.y * 32;
  int tx = threadIdx.x & 31, ty = threadIdx.x >> 5;
#pragma unroll
  for (int i = 0; i < 4; ++i)
    tile[ty + i * 8][tx] = in[(size_t)(r0 + ty + i * 8) * Cc + c0 + tx];
  __syncthreads();
#pragma unroll
  for (int i = 0; i < 4; ++i)
    out[(size_t)(c0 + ty + i * 8) * R + r0 + tx] = (__bf16)tile[tx][ty + i * 8];
}

// V part of qkvb -> vt[bh*64+d][t]  (bf16 32x32 tile transpose)
__global__ __launch_bounds__(256) void transp_v(const __bf16* __restrict__ qkv,
    __bf16* __restrict__ vtb) {
  __shared__ __bf16 tile[32][33];
  int bh = blockIdx.y >> 1, d0 = (blockIdx.y & 1) * 32;
  int b = bh >> 4, h = bh & 15;
  int t0 = blockIdx.x * 32;
  int tx = threadIdx.x & 31, ty = threadIdx.x >> 5;
#pragma unroll
  for (int i = 0; i < 4; ++i)
    tile[ty + i * 8][tx] = qkv[((size_t)b * TDIM + t0 + ty + i * 8) * QKVS + 2048 + h * DHE + d0 + tx];
  __syncthreads();
#pragma unroll
  for (int i = 0; i < 4; ++i)
    vtb[((size_t)bh * 64 + d0 + ty + i * 8) * TDIM + t0 + tx] = tile[tx][ty + i * 8];
}

// ---------------- bf16 MFMA GEMM: C[M,N] = A[M,K] @ Bt[N,K]^T ----------------
template<bool BIAS, bool RES, bool RELU, bool OUTBF>
__global__ __launch_bounds__(256) void gemm_bf16(
    const __bf16* __restrict__ Ag, const __bf16* __restrict__ Bg,
    const float* __restrict__ bias, const float* __restrict__ res,
    void* __restrict__ Cm, int M, int N, int K) {
  __shared__ __bf16 As[128 * 32];
  __shared__ __bf16 Bs[128 * 32];
  int tid = threadIdx.x;
  int lane = tid & 63, wid = tid >> 6;
  int wr = wid >> 1, wc = wid & 1;
  int m0 = blockIdx.y * 128, n0 = blockIdx.x * 128;
  int srow = tid >> 2, scol = (tid & 3) * 8;
  int l15 = lane & 15, k8 = (lane >> 4) * 8;

  f32x4 acc[4][4];
#pragma unroll
  for (int m = 0; m < 4; ++m)
#pragma unroll
    for (int n = 0; n < 4; ++n) acc[m][n] = (f32x4){0.f, 0.f, 0.f, 0.f};

  for (int k0 = 0; k0 < K; k0 += 32) {
    __syncthreads();
    gld_lds16(Ag + (size_t)(m0 + srow) * K + k0 + scol,       As + tid * 8);
    gld_lds16(Ag + (size_t)(m0 + 64 + srow) * K + k0 + scol,  As + 2048 + tid * 8);
    gld_lds16(Bg + (size_t)(n0 + srow) * K + k0 + scol,       Bs + tid * 8);
    gld_lds16(Bg + (size_t)(n0 + 64 + srow) * K + k0 + scol,  Bs + 2048 + tid * 8);
    __syncthreads();

    bf16x8 af[4], bf[4];
#pragma unroll
    for (int m = 0; m < 4; ++m)
      af[m] = *(const bf16x8*)(As + (wr * 64 + m * 16 + l15) * 32 + k8);
#pragma unroll
    for (int n = 0; n < 4; ++n)
      bf[n] = *(const bf16x8*)(Bs + (wc * 64 + n * 16 + l15) * 32 + k8);
#pragma unroll
    for (int m = 0; m < 4; ++m)
#pragma unroll
      for (int n = 0; n < 4; ++n)
        acc[m][n] = __builtin_amdgcn_mfma_f32_16x16x32_bf16(af[m], bf[n], acc[m][n], 0, 0, 0);
  }

  int rbase = (lane >> 4) * 4;
#pragma unroll
  for (int m = 0; m < 4; ++m) {
    int row = m0 + wr * 64 + m * 16 + rbase;
#pragma unroll
    for (int n = 0; n < 4; ++n) {
      int col = n0 + wc * 64 + n * 16 + l15;
#pragma unroll
      for (int j = 0; j < 4; ++j) {
        float v = acc[m][n][j];
        size_t off = (size_t)(row + j) * N + col;
        if (BIAS) v += bias[col];
        if (RES)  v += res[off];
        if (RELU) v = fmaxf(v, 0.f);
        if (OUTBF) ((__bf16*)Cm)[off] = (__bf16)v;
        else       ((float*)Cm)[off] = v;
      }
    }
  }
}

// ---------------- MFMA flash attention, bf16 in / fp32 softmax ----------------
// qkv bf16 [B*T][3072] (q@0, k@1024, v unused here), vt bf16 [bh*64+d][T].
// Block: 256 thr = 4 waves; 64 q-rows per block (16/wave); KV tile 64.
__global__ __launch_bounds__(256) void attn_mfma(const __bf16* __restrict__ qkv,
    const __bf16* __restrict__ vt, __bf16* __restrict__ o) {
  __shared__ __bf16 Ks[64][72];      // K rows [tk][d], padded (144B row -> 2-way max)
  __shared__ __bf16 Vs[64][72];      // V^T rows [d][tk]
  __shared__ __bf16 Ps[4][16][72];   // per-wave P [tq_local][tk]
  int bh = blockIdx.y;
  int b = bh >> 4, h = bh & 15;
  int bx = blockIdx.x;
  int tid = threadIdx.x;
  int lane = tid & 63, w = tid >> 6;
  int l15 = lane & 15, hi = lane >> 4;
  size_t bT = (size_t)b * TDIM;

  // hoisted Q fragments: A[m=l15][k=d], rows = bx*64 + w*16 + l15
  bf16x8 qf[2];
  {
    const __bf16* qp = qkv + (bT + bx * 64 + w * 16 + l15) * QKVS + h * DHE;
    qf[0] = *(const bf16x8*)(qp + hi * 8);
    qf[1] = *(const bf16x8*)(qp + 32 + hi * 8);
  }

  float m_i[4], l_i[4];
  f32x4 oacc[4];
#pragma unroll
  for (int r = 0; r < 4; ++r) { m_i[r] = -INFINITY; l_i[r] = 0.f; }
#pragma unroll
  for (int n = 0; n < 4; ++n) oacc[n] = (f32x4){0.f, 0.f, 0.f, 0.f};

  int r0 = tid >> 3, c8 = (tid & 7) * 8;   // staging: 8 threads/row, 16B each

  for (int t2 = 0; t2 <= bx; ++t2) {
    __syncthreads();
#pragma unroll
    for (int rr = 0; rr < 2; ++rr) {
      int row = rr * 32 + r0;
      *(bf16x8*)&Ks[row][c8] =
          *(const bf16x8*)(qkv + (bT + t2 * 64 + row) * QKVS + 1024 + h * DHE + c8);
      *(bf16x8*)&Vs[row][c8] =
          *(const bf16x8*)(vt + ((size_t)bh * 64 + row) * TDIM + t2 * 64 + c8);
    }
    __syncthreads();

    // S = Q K^T : D[m=tq(hi*4+r)][n=tk(n*16+l15)]
    f32x4 sacc[4];
#pragma unroll
    for (int n = 0; n < 4; ++n) sacc[n] = (f32x4){0.f, 0.f, 0.f, 0.f};
#pragma unroll
    for (int n = 0; n < 4; ++n)
#pragma unroll
      for (int kk = 0; kk < 2; ++kk) {
        bf16x8 kf = *(const bf16x8*)&Ks[n * 16 + l15][kk * 32 + hi * 8];
        sacc[n] = __builtin_amdgcn_mfma_f32_16x16x32_bf16(qf[kk], kf, sacc[n], 0, 0, 0);
      }

    bool diag = (t2 == bx);
    float alpha[4];
#pragma unroll
    for (int r = 0; r < 4; ++r) {
      float s[4];
#pragma unroll
      for (int n = 0; n < 4; ++n) {
        float v = sacc[n][r] * 0.03125f;   // C^-0.5 = 1/32
        if (diag && (n * 16 + l15 > w * 16 + hi * 4 + r)) v = -INFINITY;
        s[n] = v;
      }
      float mx = fmaxf(fmaxf(s[0], s[1]), fmaxf(s[2], s[3]));
#pragma unroll
      for (int off = 1; off < 16; off <<= 1) mx = fmaxf(mx, __shfl_xor(mx, off));
      float nm = fmaxf(m_i[r], mx);
      alpha[r] = __expf(m_i[r] - nm);
      m_i[r] = nm;
      float ls = 0.f;
#pragma unroll
      for (int n = 0; n < 4; ++n) {
        float p = __expf(s[n] - nm);
        ls += p;
        Ps[w][hi * 4 + r][n * 16 + l15] = (__bf16)p;
      }
#pragma unroll
      for (int off = 1; off < 16; off <<= 1) ls += __shfl_xor(ls, off);
      l_i[r] = l_i[r] * alpha[r] + ls;
    }
#pragma unroll
    for (int n = 0; n < 4; ++n)
#pragma unroll
      for (int r = 0; r < 4; ++r) oacc[n][r] *= alpha[r];

    // O += P V : A[m=tq(l15)][k=tk], B[k=tk][n=d(n*16+l15)]
    bf16x8 pa[2];
    pa[0] = *(const bf16x8*)&Ps[w][l15][hi * 8];
    pa[1] = *(const bf16x8*)&Ps[w][l15][32 + hi * 8];
#pragma unroll
    for (int n = 0; n < 4; ++n)
#pragma unroll
      for (int kk = 0; kk < 2; ++kk) {
        bf16x8 vf = *(const bf16x8*)&Vs[n * 16 + l15][kk * 32 + hi * 8];
        oacc[n] = __builtin_amdgcn_mfma_f32_16x16x32_bf16(pa[kk], vf, oacc[n], 0, 0, 0);
      }
  }

#pragma unroll
  for (int r = 0; r < 4; ++r) {
    float inv = 1.f / l_i[r];
    size_t row = bT + bx * 64 + w * 16 + hi * 4 + r;
#pragma unroll
    for (int n = 0; n < 4; ++n)
      o[row * CDIM + h * DHE + n * 16 + l15] = (__bf16)(oacc[n][r] * inv);
  }
}

// ---------------- launch ----------------
extern "C" void kernel_launch(void* const* d_in, const int* in_sizes, int n_in,
                              void* d_out, int out_size, void* d_ws, size_t ws_size,
                              hipStream_t stream) {
  (void)in_sizes; (void)n_in; (void)out_size; (void)ws_size;
  const float* x   = (const float*)d_in[0];
  const float* Wq  = (const float*)d_in[1];
  const float* Wk  = (const float*)d_in[2];
  const float* Wv  = (const float*)d_in[3];
  const float* Wo  = (const float*)d_in[4];
  const float* bo  = (const float*)d_in[5];
  const float* W1  = (const float*)d_in[6];
  const float* b1  = (const float*)d_in[7];
  const float* W2  = (const float*)d_in[8];
  const float* b2  = (const float*)d_in[9];
  const float* g1  = (const float*)d_in[10];
  const float* be1 = (const float*)d_in[11];
  const float* g2  = (const float*)d_in[12];
  const float* be2 = (const float*)d_in[13];
  float* out = (float*)d_out;

  char* wsb = (char*)d_ws;
  const size_t MB = 1024 * 1024;
  __bf16* Wqkvb = (__bf16*)(wsb + 0);
  __bf16* Wob   = (__bf16*)(wsb + 6  * MB);
  __bf16* W1b   = (__bf16*)(wsb + 8  * MB);
  __bf16* W2b   = (__bf16*)(wsb + 16 * MB);
  __bf16* qkvb  = (__bf16*)(wsb + 24 * MB);
  __bf16* hb    = (__bf16*)(wsb + 24 * MB);   // overlays qkvb+vt (dead by FFN)
  __bf16* vtb   = (__bf16*)(wsb + 48 * MB);
  __bf16* x1b   = (__bf16*)(wsb + 56 * MB);
  __bf16* attnb = (__bf16*)(wsb + 56 * MB);
  float*  xmid  = (float*) (wsb + 64 * MB);
  __bf16* x2b   = (__bf16*)(wsb + 80 * MB);
  float*  stats = (float*) (wsb + 88 * MB);
  float* sum1 = stats,        *sq1 = stats + 2048;
  float* sum2 = stats + 4096, *sq2 = stats + 6144;

  hipMemsetAsync(stats, 0, 4 * 2048 * sizeof(float), stream);

  pack_qkvT<<<dim3(32, 2, 48), 256, 0, stream>>>(Wq, Wk, Wv, Wqkvb);
  transp_bf16<<<dim3(32, 32),  256, 0, stream>>>(Wo, Wob, 1024, 1024);
  transp_bf16<<<dim3(128, 32), 256, 0, stream>>>(W1, W1b, 1024, 4096);
  transp_bf16<<<dim3(32, 128), 256, 0, stream>>>(W2, W2b, 4096, 1024);

  // LN1 -> x1b
  ln_stats<<<dim3(CDIM / 256, BDIM, 16), 256, 0, stream>>>(x, sum1, sq1);
  ln_apply<<<dim3((BDIM * TDIM * CDIM) / 256), 256, 0, stream>>>(x, sum1, sq1, g1, be1, x1b);

  // fused QKV projection (bf16 out)
  gemm_bf16<false, false, false, true><<<dim3(24, 32), 256, 0, stream>>>(
      x1b, Wqkvb, nullptr, nullptr, qkvb, 4096, 3072, 1024);

  // V transpose for PV operand
  transp_v<<<dim3(TDIM / 32, 64), 256, 0, stream>>>(qkvb, vtb);

  // MFMA flash attention -> attnb
  attn_mfma<<<dim3(TDIM / 64, BDIM * HDIM), 256, 0, stream>>>(qkvb, vtb, attnb);

  // output projection + residual
  gemm_bf16<true, true, false, false><<<dim3(8, 32), 256, 0, stream>>>(
      attnb, Wob, bo, x, xmid, 4096, 1024, 1024);

  // LN2 -> x2b
  ln_stats<<<dim3(CDIM / 256, BDIM, 16), 256, 0, stream>>>(xmid, sum2, sq2);
  ln_apply<<<dim3((BDIM * TDIM * CDIM) / 256), 256, 0, stream>>>(xmid, sum2, sq2, g2, be2, x2b);

  // FFN
  gemm_bf16<true, false, true, true><<<dim3(32, 32), 256, 0, stream>>>(
      x2b, W1b, b1, nullptr, hb, 4096, 4096, 1024);
  gemm_bf16<true, true, false, false><<<dim3(8, 32), 256, 0, stream>>>(
      hb, W2b, b2, xmid, out, 4096, 1024, 4096);
}

// Round 4
// 326.533 us; speedup vs baseline: 6.1898x; 1.1828x over previous
//
#include <hip/hip_runtime.h>
#include <math.h>

// Transformer block. bf16 MFMA GEMMs (128x128 tile) + bf16 MFMA flash attention
// with paired q-tiles + split-KV wave groups (load-balanced, occupancy-flat).
// B=2 T=2048 C=1024 H=16 DH=64 F=4096. LN over TIME axis (ddof=1).
//
// Workspace (byte offsets):
//   [0,6M)     Wqkvb bf16 [3072][1024]  ([N][K])
//   [6M,8M)    Wob   bf16 [1024][1024]
//   [8M,16M)   W1b   bf16 [4096][1024]
//   [16M,24M)  W2b   bf16 [1024][4096]
//   [24M,48M)  qkvb  bf16 [4096][3072]   \ overlaid by hb bf16 [4096][4096] ([24M,56M))
//   [48M,56M)  vt    bf16 [2048][2048]   /   (both dead before FFN)
//   [56M,64M)  x1b bf16, then attnb bf16 [4096][1024]
//   [64M,80M)  xmid fp32 [4096][1024]
//   [80M,88M)  x2b bf16
//   [88M,88M+32K) LN stats

#define TDIM 2048
#define BDIM 2
#define CDIM 1024
#define HDIM 16
#define DHE  64
#define QKVS 3072
#define NT   32          // T/64 q-tiles
#define LNEPS 1e-5f

typedef float f32x4 __attribute__((ext_vector_type(4)));
typedef __bf16 bf16x8 __attribute__((ext_vector_type(8)));

__device__ __forceinline__ void gld_lds16(const __bf16* g, __bf16* l) {
  __builtin_amdgcn_global_load_lds(
      (const __attribute__((address_space(1))) void*)g,
      (__attribute__((address_space(3))) void*)l, 16, 0, 0);
}

// ---------------- LayerNorm over T ----------------
__global__ __launch_bounds__(256) void ln_stats(const float* __restrict__ x,
                                                float* __restrict__ sumv,
                                                float* __restrict__ sqv) {
  int c = blockIdx.x * 256 + threadIdx.x;
  int b = blockIdx.y;
  int t0 = blockIdx.z * (TDIM / 16);
  const float* xp = x + ((size_t)b * TDIM + t0) * CDIM + c;
  float s = 0.f, q = 0.f;
  for (int t = 0; t < TDIM / 16; ++t) {
    float v = xp[(size_t)t * CDIM];
    s += v;
    q += v * v;
  }
  atomicAdd(&sumv[b * CDIM + c], s);
  atomicAdd(&sqv[b * CDIM + c], q);
}

__global__ __launch_bounds__(256) void ln_apply(const float* __restrict__ x,
    const float* __restrict__ sumv, const float* __restrict__ sqv,
    const float* __restrict__ gamma, const float* __restrict__ beta,
    __bf16* __restrict__ y) {
  size_t i = (size_t)blockIdx.x * 256 + threadIdx.x;
  int c = (int)(i & (CDIM - 1));
  int b = (int)(i >> 21);
  float mean = sumv[b * CDIM + c] * (1.f / TDIM);
  float var = (sqv[b * CDIM + c] - mean * mean * (float)TDIM) * (1.f / (TDIM - 1));
  float rstd = rsqrtf(var + LNEPS);
  y[i] = (__bf16)(gamma[c] * (x[i] - mean) * rstd + beta[c]);
}

// ---------------- weight repacks (transposed, bf16, [N][K]) ----------------
__global__ __launch_bounds__(256) void pack_qkvT(const float* __restrict__ Wq,
    const float* __restrict__ Wk, const float* __restrict__ Wv,
    __bf16* __restrict__ out) {
  __shared__ float tile[32][33];
  int mat = blockIdx.z >> 4, h = blockIdx.z & 15;
  const float* W = (mat == 0) ? Wq : (mat == 1) ? Wk : Wv;
  int c0 = blockIdx.x * 32, d0 = blockIdx.y * 32;
  int tx = threadIdx.x & 31, ty = threadIdx.x >> 5;
#pragma unroll
  for (int i = 0; i < 4; ++i)
    tile[ty + i * 8][tx] = W[((size_t)h * CDIM + c0 + ty + i * 8) * DHE + d0 + tx];
  __syncthreads();
#pragma unroll
  for (int i = 0; i < 4; ++i) {
    int n = mat * 1024 + h * 64 + d0 + ty + i * 8;
    out[(size_t)n * CDIM + c0 + tx] = (__bf16)tile[tx][ty + i * 8];
  }
}

__global__ __launch_bounds__(256) void transp_bf16(const float* __restrict__ in,
    __bf16* __restrict__ out, int R, int Cc) {
  __shared__ float tile[32][33];
  int c0 = blockIdx.x * 32, r0 = blockIdx.y * 32;
  int tx = threadIdx.x & 31, ty = threadIdx.x >> 5;
#pragma unroll
  for (int i = 0; i < 4; ++i)
    tile[ty + i * 8][tx] = in[(size_t)(r0 + ty + i * 8) * Cc + c0 + tx];
  __syncthreads();
#pragma unroll
  for (int i = 0; i < 4; ++i)
    out[(size_t)(c0 + ty + i * 8) * R + r0 + tx] = (__bf16)tile[tx][ty + i * 8];
}

// V part of qkvb -> vt[bh*64+d][t]  (bf16 32x32 tile transpose)
__global__ __launch_bounds__(256) void transp_v(const __bf16* __restrict__ qkv,
    __bf16* __restrict__ vtb) {
  __shared__ __bf16 tile[32][33];
  int bh = blockIdx.y >> 1, d0 = (blockIdx.y & 1) * 32;
  int b = bh >> 4, h = bh & 15;
  int t0 = blockIdx.x * 32;
  int tx = threadIdx.x & 31, ty = threadIdx.x >> 5;
#pragma unroll
  for (int i = 0; i < 4; ++i)
    tile[ty + i * 8][tx] = qkv[((size_t)b * TDIM + t0 + ty + i * 8) * QKVS + 2048 + h * DHE + d0 + tx];
  __syncthreads();
#pragma unroll
  for (int i = 0; i < 4; ++i)
    vtb[((size_t)bh * 64 + d0 + ty + i * 8) * TDIM + t0 + tx] = tile[tx][ty + i * 8];
}

// ---------------- bf16 MFMA GEMM: C[M,N] = A[M,K] @ Bt[N,K]^T ----------------
template<bool BIAS, bool RES, bool RELU, bool OUTBF>
__global__ __launch_bounds__(256) void gemm_bf16(
    const __bf16* __restrict__ Ag, const __bf16* __restrict__ Bg,
    const float* __restrict__ bias, const float* __restrict__ res,
    void* __restrict__ Cm, int M, int N, int K) {
  __shared__ __bf16 As[128 * 32];
  __shared__ __bf16 Bs[128 * 32];
  int tid = threadIdx.x;
  int lane = tid & 63, wid = tid >> 6;
  int wr = wid >> 1, wc = wid & 1;
  int m0 = blockIdx.y * 128, n0 = blockIdx.x * 128;
  int srow = tid >> 2, scol = (tid & 3) * 8;
  int l15 = lane & 15, k8 = (lane >> 4) * 8;

  f32x4 acc[4][4];
#pragma unroll
  for (int m = 0; m < 4; ++m)
#pragma unroll
    for (int n = 0; n < 4; ++n) acc[m][n] = (f32x4){0.f, 0.f, 0.f, 0.f};

  for (int k0 = 0; k0 < K; k0 += 32) {
    __syncthreads();
    gld_lds16(Ag + (size_t)(m0 + srow) * K + k0 + scol,       As + tid * 8);
    gld_lds16(Ag + (size_t)(m0 + 64 + srow) * K + k0 + scol,  As + 2048 + tid * 8);
    gld_lds16(Bg + (size_t)(n0 + srow) * K + k0 + scol,       Bs + tid * 8);
    gld_lds16(Bg + (size_t)(n0 + 64 + srow) * K + k0 + scol,  Bs + 2048 + tid * 8);
    __syncthreads();

    bf16x8 af[4], bf[4];
#pragma unroll
    for (int m = 0; m < 4; ++m)
      af[m] = *(const bf16x8*)(As + (wr * 64 + m * 16 + l15) * 32 + k8);
#pragma unroll
    for (int n = 0; n < 4; ++n)
      bf[n] = *(const bf16x8*)(Bs + (wc * 64 + n * 16 + l15) * 32 + k8);
#pragma unroll
    for (int m = 0; m < 4; ++m)
#pragma unroll
      for (int n = 0; n < 4; ++n)
        acc[m][n] = __builtin_amdgcn_mfma_f32_16x16x32_bf16(af[m], bf[n], acc[m][n], 0, 0, 0);
  }

  int rbase = (lane >> 4) * 4;
#pragma unroll
  for (int m = 0; m < 4; ++m) {
    int row = m0 + wr * 64 + m * 16 + rbase;
#pragma unroll
    for (int n = 0; n < 4; ++n) {
      int col = n0 + wc * 64 + n * 16 + l15;
#pragma unroll
      for (int j = 0; j < 4; ++j) {
        float v = acc[m][n][j];
        size_t off = (size_t)(row + j) * N + col;
        if (BIAS) v += bias[col];
        if (RES)  v += res[off];
        if (RELU) v = fmaxf(v, 0.f);
        if (OUTBF) ((__bf16*)Cm)[off] = (__bf16)v;
        else       ((float*)Cm)[off] = v;
      }
    }
  }
}

// ---------------- MFMA flash attention, paired q-tiles + split-KV ----------------
// Block: 512 thr = 8 waves. Waves 0-3 (group 0) stage/process even KV tiles,
// waves 4-7 (group 1) odd tiles, into separate LDS buffers. Each block handles
// q-tiles bxA=blockIdx.x and bxB=31-bxA (uniform 33 tile-units/block).
// Groups keep independent online-softmax state; exact flash-merge in epilogue.
__global__ __launch_bounds__(512, 4) void attn_mfma(const __bf16* __restrict__ qkv,
    const __bf16* __restrict__ vt, __bf16* __restrict__ o) {
  __shared__ __align__(16) char smem[55296];
  __bf16 (*Ks)[64][72] = (__bf16 (*)[64][72])(smem);            // [2][64][72]
  __bf16 (*Vs)[64][72] = (__bf16 (*)[64][72])(smem + 18432);    // [2][64][72]
  __bf16 (*Ps)[16][72] = (__bf16 (*)[16][72])(smem + 36864);    // [8][16][72]
  float (*Os)[64]      = (float (*)[64])(smem);                 // merge overlay
  float* ms = (float*)(smem + 16384);
  float* ls = (float*)(smem + 16640);

  int bh = blockIdx.y;
  int b = bh >> 4, h = bh & 15;
  int bxA = blockIdx.x;        // 0..15
  int bxB = NT - 1 - bxA;      // 31..16
  int tid = threadIdx.x;
  int lane = tid & 63, w = tid >> 6;   // w 0..7
  int wq = w & 3;                      // q-row wave slot
  int g = w >> 2;                      // KV parity group
  int l15 = lane & 15, hi = lane >> 4;
  size_t bT = (size_t)b * TDIM;

  // hoisted Q fragments for both q-tiles: A[m=l15][k=d]
  bf16x8 qfA[2], qfB[2];
  {
    const __bf16* qp = qkv + (bT + bxA * 64 + wq * 16 + l15) * QKVS + h * DHE;
    qfA[0] = *(const bf16x8*)(qp + hi * 8);
    qfA[1] = *(const bf16x8*)(qp + 32 + hi * 8);
    qp = qkv + (bT + bxB * 64 + wq * 16 + l15) * QKVS + h * DHE;
    qfB[0] = *(const bf16x8*)(qp + hi * 8);
    qfB[1] = *(const bf16x8*)(qp + 32 + hi * 8);
  }

  float mA[4], lA[4], mB[4], lB[4];
  f32x4 oA[4], oB[4];
#pragma unroll
  for (int r = 0; r < 4; ++r) {
    mA[r] = -INFINITY; lA[r] = 0.f; mB[r] = -INFINITY; lB[r] = 0.f;
    oA[r] = (f32x4){0.f, 0.f, 0.f, 0.f};
    oB[r] = (f32x4){0.f, 0.f, 0.f, 0.f};
  }

  int g_tid = tid & 255;
  int r0 = g_tid >> 3, c8 = (g_tid & 7) * 8;   // staging within group

  // process one staged KV tile for one q-tile
  auto process = [&](const bf16x8* qf, float* m_i, float* l_i, f32x4* oacc,
                     int bx, int t2) {
    f32x4 sacc[4];
#pragma unroll
    for (int n = 0; n < 4; ++n) sacc[n] = (f32x4){0.f, 0.f, 0.f, 0.f};
    __builtin_amdgcn_s_setprio(1);
#pragma unroll
    for (int n = 0; n < 4; ++n)
#pragma unroll
      for (int kk = 0; kk < 2; ++kk) {
        bf16x8 kf = *(const bf16x8*)&Ks[g][n * 16 + l15][kk * 32 + hi * 8];
        sacc[n] = __builtin_amdgcn_mfma_f32_16x16x32_bf16(qf[kk], kf, sacc[n], 0, 0, 0);
      }
    __builtin_amdgcn_s_setprio(0);

    bool diag = (t2 == bx);
    float alpha[4];
#pragma unroll
    for (int r = 0; r < 4; ++r) {
      float s[4];
#pragma unroll
      for (int n = 0; n < 4; ++n) {
        float v = sacc[n][r] * 0.03125f;   // C^-0.5 = 1/32
        if (diag && (n * 16 + l15 > wq * 16 + hi * 4 + r)) v = -INFINITY;
        s[n] = v;
      }
      float mx = fmaxf(fmaxf(s[0], s[1]), fmaxf(s[2], s[3]));
#pragma unroll
      for (int off = 1; off < 16; off <<= 1) mx = fmaxf(mx, __shfl_xor(mx, off));
      float nm = fmaxf(m_i[r], mx);
      alpha[r] = __expf(m_i[r] - nm);
      m_i[r] = nm;
      float lsm = 0.f;
#pragma unroll
      for (int n = 0; n < 4; ++n) {
        float p = __expf(s[n] - nm);
        lsm += p;
        Ps[w][hi * 4 + r][n * 16 + l15] = (__bf16)p;
      }
#pragma unroll
      for (int off = 1; off < 16; off <<= 1) lsm += __shfl_xor(lsm, off);
      l_i[r] = l_i[r] * alpha[r] + lsm;
    }
#pragma unroll
    for (int n = 0; n < 4; ++n)
#pragma unroll
      for (int r = 0; r < 4; ++r) oacc[n][r] *= alpha[r];

    bf16x8 pa[2];
    pa[0] = *(const bf16x8*)&Ps[w][l15][hi * 8];
    pa[1] = *(const bf16x8*)&Ps[w][l15][32 + hi * 8];
    __builtin_amdgcn_s_setprio(1);
#pragma unroll
    for (int n = 0; n < 4; ++n)
#pragma unroll
      for (int kk = 0; kk < 2; ++kk) {
        bf16x8 vf = *(const bf16x8*)&Vs[g][n * 16 + l15][kk * 32 + hi * 8];
        oacc[n] = __builtin_amdgcn_mfma_f32_16x16x32_bf16(pa[kk], vf, oacc[n], 0, 0, 0);
      }
    __builtin_amdgcn_s_setprio(0);
  };

  // main loop: group g owns KV tiles t2 = 2j+g. Loop bound block-uniform.
  for (int j = 0; j <= bxB / 2; ++j) {
    int t2 = 2 * j + g;
    bool have = (t2 <= bxB);
    __syncthreads();   // prior iteration's frag reads done
    if (have) {
#pragma unroll
      for (int rr = 0; rr < 2; ++rr) {
        int row = rr * 32 + r0;
        *(bf16x8*)&Ks[g][row][c8] =
            *(const bf16x8*)(qkv + (bT + t2 * 64 + row) * QKVS + 1024 + h * DHE + c8);
        *(bf16x8*)&Vs[g][row][c8] =
            *(const bf16x8*)(vt + ((size_t)bh * 64 + row) * TDIM + t2 * 64 + c8);
      }
    }
    __syncthreads();   // staging visible to group
    if (t2 <= bxA) process(qfA, mA, lA, oA, bxA, t2);
    if (have)      process(qfB, mB, lB, oB, bxB, t2);
  }

  // epilogue: exact flash-merge of the two groups' partial states, per q-tile
  auto merge = [&](int bx, float* m_i, float* l_i, f32x4* oacc) {
    __syncthreads();   // main-loop / previous-merge LDS use done
    if (g == 1) {
#pragma unroll
      for (int r = 0; r < 4; ++r) {
        int lrow = wq * 16 + hi * 4 + r;
        if (l15 == 0) { ms[lrow] = m_i[r]; ls[lrow] = l_i[r]; }
#pragma unroll
        for (int n = 0; n < 4; ++n)
          Os[lrow][n * 16 + l15] = oacc[n][r];
      }
    }
    __syncthreads();
    if (g == 0) {
#pragma unroll
      for (int r = 0; r < 4; ++r) {
        int lrow = wq * 16 + hi * 4 + r;
        float m1 = ms[lrow], l1 = ls[lrow];
        float mm = fmaxf(m_i[r], m1);
        float e0 = __expf(m_i[r] - mm), e1 = __expf(m1 - mm);
        float inv = 1.f / (l_i[r] * e0 + l1 * e1);
        size_t row = bT + bx * 64 + lrow;
#pragma unroll
        for (int n = 0; n < 4; ++n) {
          float v = (oacc[n][r] * e0 + Os[lrow][n * 16 + l15] * e1) * inv;
          o[row * CDIM + h * DHE + n * 16 + l15] = (__bf16)v;
        }
      }
    }
  };
  merge(bxA, mA, lA, oA);
  merge(bxB, mB, lB, oB);
}

// ---------------- launch ----------------
extern "C" void kernel_launch(void* const* d_in, const int* in_sizes, int n_in,
                              void* d_out, int out_size, void* d_ws, size_t ws_size,
                              hipStream_t stream) {
  (void)in_sizes; (void)n_in; (void)out_size; (void)ws_size;
  const float* x   = (const float*)d_in[0];
  const float* Wq  = (const float*)d_in[1];
  const float* Wk  = (const float*)d_in[2];
  const float* Wv  = (const float*)d_in[3];
  const float* Wo  = (const float*)d_in[4];
  const float* bo  = (const float*)d_in[5];
  const float* W1  = (const float*)d_in[6];
  const float* b1  = (const float*)d_in[7];
  const float* W2  = (const float*)d_in[8];
  const float* b2  = (const float*)d_in[9];
  const float* g1  = (const float*)d_in[10];
  const float* be1 = (const float*)d_in[11];
  const float* g2  = (const float*)d_in[12];
  const float* be2 = (const float*)d_in[13];
  float* out = (float*)d_out;

  char* wsb = (char*)d_ws;
  const size_t MB = 1024 * 1024;
  __bf16* Wqkvb = (__bf16*)(wsb + 0);
  __bf16* Wob   = (__bf16*)(wsb + 6  * MB);
  __bf16* W1b   = (__bf16*)(wsb + 8  * MB);
  __bf16* W2b   = (__bf16*)(wsb + 16 * MB);
  __bf16* qkvb  = (__bf16*)(wsb + 24 * MB);
  __bf16* hb    = (__bf16*)(wsb + 24 * MB);   // overlays qkvb+vt (dead by FFN)
  __bf16* vtb   = (__bf16*)(wsb + 48 * MB);
  __bf16* x1b   = (__bf16*)(wsb + 56 * MB);
  __bf16* attnb = (__bf16*)(wsb + 56 * MB);
  float*  xmid  = (float*) (wsb + 64 * MB);
  __bf16* x2b   = (__bf16*)(wsb + 80 * MB);
  float*  stats = (float*) (wsb + 88 * MB);
  float* sum1 = stats,        *sq1 = stats + 2048;
  float* sum2 = stats + 4096, *sq2 = stats + 6144;

  hipMemsetAsync(stats, 0, 4 * 2048 * sizeof(float), stream);

  pack_qkvT<<<dim3(32, 2, 48), 256, 0, stream>>>(Wq, Wk, Wv, Wqkvb);
  transp_bf16<<<dim3(32, 32),  256, 0, stream>>>(Wo, Wob, 1024, 1024);
  transp_bf16<<<dim3(128, 32), 256, 0, stream>>>(W1, W1b, 1024, 4096);
  transp_bf16<<<dim3(32, 128), 256, 0, stream>>>(W2, W2b, 4096, 1024);

  // LN1 -> x1b
  ln_stats<<<dim3(CDIM / 256, BDIM, 16), 256, 0, stream>>>(x, sum1, sq1);
  ln_apply<<<dim3((BDIM * TDIM * CDIM) / 256), 256, 0, stream>>>(x, sum1, sq1, g1, be1, x1b);

  // fused QKV projection (bf16 out)
  gemm_bf16<false, false, false, true><<<dim3(24, 32), 256, 0, stream>>>(
      x1b, Wqkvb, nullptr, nullptr, qkvb, 4096, 3072, 1024);

  // V transpose for PV operand
  transp_v<<<dim3(TDIM / 32, 64), 256, 0, stream>>>(qkvb, vtb);

  // MFMA flash attention (paired q-tiles, split-KV) -> attnb
  attn_mfma<<<dim3(NT / 2, BDIM * HDIM), 512, 0, stream>>>(qkvb, vtb, attnb);

  // output projection + residual
  gemm_bf16<true, true, false, false><<<dim3(8, 32), 256, 0, stream>>>(
      attnb, Wob, bo, x, xmid, 4096, 1024, 1024);

  // LN2 -> x2b
  ln_stats<<<dim3(CDIM / 256, BDIM, 16), 256, 0, stream>>>(xmid, sum2, sq2);
  ln_apply<<<dim3((BDIM * TDIM * CDIM) / 256), 256, 0, stream>>>(xmid, sum2, sq2, g2, be2, x2b);

  // FFN
  gemm_bf16<true, false, true, true><<<dim3(32, 32), 256, 0, stream>>>(
      x2b, W1b, b1, nullptr, hb, 4096, 4096, 1024);
  gemm_bf16<true, true, false, false><<<dim3(8, 32), 256, 0, stream>>>(
      hb, W2b, b2, xmid, out, 4096, 1024, 4096);
}

// Round 5
// 312.386 us; speedup vs baseline: 6.4702x; 1.0453x over previous
//
#include <hip/hip_runtime.h>
#include <math.h>

// Transformer block. bf16 MFMA GEMMs + bf16 MFMA flash attention.
// New this round: 256x256 8-wave deep-pipelined GEMM (T1 XCD swizzle, T2 LDS
// XOR swizzle, T3/T4 phased schedule w/ counted vmcnt, T5 setprio) for QKV+FFN1.
// B=2 T=2048 C=1024 H=16 DH=64 F=4096. LN over TIME axis (ddof=1).
//
// Workspace (byte offsets):
//   [0,6M)     Wqkvb bf16 [3072][1024]  ([N][K])
//   [6M,8M)    Wob   bf16 [1024][1024]
//   [8M,16M)   W1b   bf16 [4096][1024]
//   [16M,24M)  W2b   bf16 [1024][4096]
//   [24M,48M)  qkvb  bf16 [4096][3072]   \ overlaid by hb bf16 [4096][4096] ([24M,56M))
//   [48M,56M)  vt    bf16 [2048][2048]   /   (both dead before FFN)
//   [56M,64M)  x1b bf16, then attnb bf16 [4096][1024]
//   [64M,80M)  xmid fp32 [4096][1024]
//   [80M,88M)  x2b bf16
//   [88M,88M+32K) LN stats

#define TDIM 2048
#define BDIM 2
#define CDIM 1024
#define HDIM 16
#define DHE  64
#define QKVS 3072
#define NT   32          // T/64 q-tiles
#define LNEPS 1e-5f

typedef float f32x4 __attribute__((ext_vector_type(4)));
typedef __bf16 bf16x8 __attribute__((ext_vector_type(8)));

__device__ __forceinline__ void gld_lds16(const __bf16* g, __bf16* l) {
  __builtin_amdgcn_global_load_lds(
      (const __attribute__((address_space(1))) void*)g,
      (__attribute__((address_space(3))) void*)l, 16, 0, 0);
}

// ---------------- LayerNorm over T ----------------
__global__ __launch_bounds__(256) void ln_stats(const float* __restrict__ x,
                                                float* __restrict__ sumv,
                                                float* __restrict__ sqv) {
  int c = blockIdx.x * 256 + threadIdx.x;
  int b = blockIdx.y;
  int t0 = blockIdx.z * (TDIM / 16);
  const float* xp = x + ((size_t)b * TDIM + t0) * CDIM + c;
  float s = 0.f, q = 0.f;
  for (int t = 0; t < TDIM / 16; ++t) {
    float v = xp[(size_t)t * CDIM];
    s += v;
    q += v * v;
  }
  atomicAdd(&sumv[b * CDIM + c], s);
  atomicAdd(&sqv[b * CDIM + c], q);
}

__global__ __launch_bounds__(256) void ln_apply(const float* __restrict__ x,
    const float* __restrict__ sumv, const float* __restrict__ sqv,
    const float* __restrict__ gamma, const float* __restrict__ beta,
    __bf16* __restrict__ y) {
  size_t i = (size_t)blockIdx.x * 256 + threadIdx.x;
  int c = (int)(i & (CDIM - 1));
  int b = (int)(i >> 21);
  float mean = sumv[b * CDIM + c] * (1.f / TDIM);
  float var = (sqv[b * CDIM + c] - mean * mean * (float)TDIM) * (1.f / (TDIM - 1));
  float rstd = rsqrtf(var + LNEPS);
  y[i] = (__bf16)(gamma[c] * (x[i] - mean) * rstd + beta[c]);
}

// ---------------- weight repacks (transposed, bf16, [N][K]) ----------------
__global__ __launch_bounds__(256) void pack_qkvT(const float* __restrict__ Wq,
    const float* __restrict__ Wk, const float* __restrict__ Wv,
    __bf16* __restrict__ out) {
  __shared__ float tile[32][33];
  int mat = blockIdx.z >> 4, h = blockIdx.z & 15;
  const float* W = (mat == 0) ? Wq : (mat == 1) ? Wk : Wv;
  int c0 = blockIdx.x * 32, d0 = blockIdx.y * 32;
  int tx = threadIdx.x & 31, ty = threadIdx.x >> 5;
#pragma unroll
  for (int i = 0; i < 4; ++i)
    tile[ty + i * 8][tx] = W[((size_t)h * CDIM + c0 + ty + i * 8) * DHE + d0 + tx];
  __syncthreads();
#pragma unroll
  for (int i = 0; i < 4; ++i) {
    int n = mat * 1024 + h * 64 + d0 + ty + i * 8;
    out[(size_t)n * CDIM + c0 + tx] = (__bf16)tile[tx][ty + i * 8];
  }
}

__global__ __launch_bounds__(256) void transp_bf16(const float* __restrict__ in,
    __bf16* __restrict__ out, int R, int Cc) {
  __shared__ float tile[32][33];
  int c0 = blockIdx.x * 32, r0 = blockIdx.y * 32;
  int tx = threadIdx.x & 31, ty = threadIdx.x >> 5;
#pragma unroll
  for (int i = 0; i < 4; ++i)
    tile[ty + i * 8][tx] = in[(size_t)(r0 + ty + i * 8) * Cc + c0 + tx];
  __syncthreads();
#pragma unroll
  for (int i = 0; i < 4; ++i)
    out[(size_t)(c0 + ty + i * 8) * R + r0 + tx] = (__bf16)tile[tx][ty + i * 8];
}

// V part of qkvb -> vt[bh*64+d][t]
__global__ __launch_bounds__(256) void transp_v(const __bf16* __restrict__ qkv,
    __bf16* __restrict__ vtb) {
  __shared__ __bf16 tile[32][33];
  int bh = blockIdx.y >> 1, d0 = (blockIdx.y & 1) * 32;
  int b = bh >> 4, h = bh & 15;
  int t0 = blockIdx.x * 32;
  int tx = threadIdx.x & 31, ty = threadIdx.x >> 5;
#pragma unroll
  for (int i = 0; i < 4; ++i)
    tile[ty + i * 8][tx] = qkv[((size_t)b * TDIM + t0 + ty + i * 8) * QKVS + 2048 + h * DHE + d0 + tx];
  __syncthreads();
#pragma unroll
  for (int i = 0; i < 4; ++i)
    vtb[((size_t)bh * 64 + d0 + ty + i * 8) * TDIM + t0 + tx] = tile[tx][ty + i * 8];
}

// ---------------- 128x128 bf16 MFMA GEMM (kept for N=1024 shapes) ----------------
template<bool BIAS, bool RES, bool RELU, bool OUTBF>
__global__ __launch_bounds__(256) void gemm_bf16(
    const __bf16* __restrict__ Ag, const __bf16* __restrict__ Bg,
    const float* __restrict__ bias, const float* __restrict__ res,
    void* __restrict__ Cm, int M, int N, int K) {
  __shared__ __bf16 As[128 * 32];
  __shared__ __bf16 Bs[128 * 32];
  int tid = threadIdx.x;
  int lane = tid & 63, wid = tid >> 6;
  int wr = wid >> 1, wc = wid & 1;
  int m0 = blockIdx.y * 128, n0 = blockIdx.x * 128;
  int srow = tid >> 2, scol = (tid & 3) * 8;
  int l15 = lane & 15, k8 = (lane >> 4) * 8;

  f32x4 acc[4][4];
#pragma unroll
  for (int m = 0; m < 4; ++m)
#pragma unroll
    for (int n = 0; n < 4; ++n) acc[m][n] = (f32x4){0.f, 0.f, 0.f, 0.f};

  for (int k0 = 0; k0 < K; k0 += 32) {
    __syncthreads();
    gld_lds16(Ag + (size_t)(m0 + srow) * K + k0 + scol,       As + tid * 8);
    gld_lds16(Ag + (size_t)(m0 + 64 + srow) * K + k0 + scol,  As + 2048 + tid * 8);
    gld_lds16(Bg + (size_t)(n0 + srow) * K + k0 + scol,       Bs + tid * 8);
    gld_lds16(Bg + (size_t)(n0 + 64 + srow) * K + k0 + scol,  Bs + 2048 + tid * 8);
    __syncthreads();

    bf16x8 af[4], bf[4];
#pragma unroll
    for (int m = 0; m < 4; ++m)
      af[m] = *(const bf16x8*)(As + (wr * 64 + m * 16 + l15) * 32 + k8);
#pragma unroll
    for (int n = 0; n < 4; ++n)
      bf[n] = *(const bf16x8*)(Bs + (wc * 64 + n * 16 + l15) * 32 + k8);
#pragma unroll
    for (int m = 0; m < 4; ++m)
#pragma unroll
      for (int n = 0; n < 4; ++n)
        acc[m][n] = __builtin_amdgcn_mfma_f32_16x16x32_bf16(af[m], bf[n], acc[m][n], 0, 0, 0);
  }

  int rbase = (lane >> 4) * 4;
#pragma unroll
  for (int m = 0; m < 4; ++m) {
    int row = m0 + wr * 64 + m * 16 + rbase;
#pragma unroll
    for (int n = 0; n < 4; ++n) {
      int col = n0 + wc * 64 + n * 16 + l15;
#pragma unroll
      for (int j = 0; j < 4; ++j) {
        float v = acc[m][n][j];
        size_t off = (size_t)(row + j) * N + col;
        if (BIAS) v += bias[col];
        if (RES)  v += res[off];
        if (RELU) v = fmaxf(v, 0.f);
        if (OUTBF) ((__bf16*)Cm)[off] = (__bf16)v;
        else       ((float*)Cm)[off] = v;
      }
    }
  }
}

// ---------------- 256x256 8-wave deep-pipelined GEMM ----------------
// C[M,N] = A[M,K] @ Bt[N,K]^T. BK=64, 2 LDS buffers (A 32K + B 32K each).
// Per K-tile: 4 phases, Gray quadrant order (0,0)(1,0)(1,1)(0,1); each phase
// stages one 128x64 half-tile of K-tile kt+1 (order A0,B0,A1,B1) and waits
// vmcnt(4) at phases 1,2,4 (counted: stages stay in flight across barriers).
// LDS 16B-slot XOR swizzle (slot ^= row&7) applied via pre-swizzled global
// source (global_load_lds writes linearly) and swizzled ds_read cols.
template<bool BIAS, bool RELU, bool OUTBF>
__global__ __launch_bounds__(512, 2) void gemm256(
    const __bf16* __restrict__ Ag, const __bf16* __restrict__ Bg,
    const float* __restrict__ bias, void* __restrict__ Cm,
    int M, int N, int K, int gnx) {
  __shared__ __align__(16) char lds[131072];
  int tid = threadIdx.x;
  int lane = tid & 63, wid = tid >> 6;
  int wm = wid >> 2, wn = wid & 3;
  int l15 = lane & 15, hi = lane >> 4;

  // T1: bijective XCD swizzle (m204)
  int nwg = gridDim.x;
  int q = nwg >> 3, r = nwg & 7;
  int xcd = blockIdx.x & 7, pos = blockIdx.x >> 3;
  int wgid = (xcd < r ? xcd * (q + 1) : r * (q + 1) + (xcd - r) * q) + pos;
  int m0 = (wgid / gnx) * 256, n0 = (wgid % gnx) * 256;

  int sr = tid >> 3;                       // staging row in 64-row call
  int skcol = ((tid & 7) ^ (sr & 7)) << 3; // pre-swizzled source k-col (elems)

  const int ac0 = (hi * 16) ^ ((l15 & 7) << 4);  // swizzled read col, kk=0
  const int ac1 = ac0 ^ 64;                      // kk=1

  f32x4 acc[8][4];
#pragma unroll
  for (int i = 0; i < 8; ++i)
#pragma unroll
    for (int j = 0; j < 4; ++j) acc[i][j] = (f32x4){0.f, 0.f, 0.f, 0.f};

  // stage one 128x64 half-tile (2 gload_lds per wave)
  auto stage = [&](const __bf16* __restrict__ G, int grow0, int k0, char* dst) {
#pragma unroll
    for (int c = 0; c < 2; ++c)
      gld_lds16(G + (size_t)(grow0 + c * 64 + sr) * K + k0 + skcol,
                (__bf16*)(dst + c * 8192) + (size_t)tid * 8);
  };

  int KT = K >> 6;
  // prologue: K-tile 0 -> buf0, order A0,B0,A1,B1
  stage(Ag, m0,       0, lds);
  stage(Bg, n0,       0, lds + 32768);
  stage(Ag, m0 + 128, 0, lds + 16384);
  stage(Bg, n0 + 128, 0, lds + 32768 + 16384);
  asm volatile("s_waitcnt vmcnt(4)" ::: "memory");   // A0,B0 landed
  __builtin_amdgcn_s_barrier();
  asm volatile("" ::: "memory");

  bf16x8 a[4][2], b[2][2];

#define LOADA(MH) do { \
    const char* Ac_ = lds + (size_t)cur * 65536; \
    int rb_ = (wm * 128 + (MH) * 64 + l15) * 128; \
    _Pragma("unroll") \
    for (int i_ = 0; i_ < 4; ++i_) { \
      a[i_][0] = *(const bf16x8*)(Ac_ + rb_ + i_ * 2048 + ac0); \
      a[i_][1] = *(const bf16x8*)(Ac_ + rb_ + i_ * 2048 + ac1); \
    } } while (0)
#define LOADB(NH) do { \
    const char* Bc_ = lds + (size_t)cur * 65536 + 32768; \
    int rb_ = (wn * 64 + (NH) * 32 + l15) * 128; \
    _Pragma("unroll") \
    for (int j_ = 0; j_ < 2; ++j_) { \
      b[j_][0] = *(const bf16x8*)(Bc_ + rb_ + j_ * 2048 + ac0); \
      b[j_][1] = *(const bf16x8*)(Bc_ + rb_ + j_ * 2048 + ac1); \
    } } while (0)
#define QUAD(MH, NH) do { \
    __builtin_amdgcn_s_setprio(1); \
    _Pragma("unroll") \
    for (int i_ = 0; i_ < 4; ++i_) \
    _Pragma("unroll") \
    for (int j_ = 0; j_ < 2; ++j_) { \
      acc[(MH)*4+i_][(NH)*2+j_] = __builtin_amdgcn_mfma_f32_16x16x32_bf16( \
          a[i_][0], b[j_][0], acc[(MH)*4+i_][(NH)*2+j_], 0, 0, 0); \
      acc[(MH)*4+i_][(NH)*2+j_] = __builtin_amdgcn_mfma_f32_16x16x32_bf16( \
          a[i_][1], b[j_][1], acc[(MH)*4+i_][(NH)*2+j_], 0, 0, 0); \
    } \
    __builtin_amdgcn_s_setprio(0); } while (0)

  for (int kt = 0; kt < KT; ++kt) {
    int cur = kt & 1;
    char* Lnxt = lds + (size_t)(cur ^ 1) * 65536;
    int k1 = (kt + 1) << 6;
    bool notlast = (kt < KT - 1);

    // phase 1: Q(0,0) | stage A0'
    LOADA(0); LOADB(0);
    if (notlast) stage(Ag, m0, k1, Lnxt);
    __builtin_amdgcn_s_barrier();
    asm volatile("" ::: "memory");
    QUAD(0, 0);
    if (notlast) asm volatile("s_waitcnt vmcnt(4)" ::: "memory");
    else         asm volatile("s_waitcnt vmcnt(2)" ::: "memory");
    __builtin_amdgcn_s_barrier();
    asm volatile("" ::: "memory");

    // phase 2: Q(1,0) | stage B0'
    LOADA(1);
    if (notlast) stage(Bg, n0, k1, Lnxt + 32768);
    __builtin_amdgcn_s_barrier();
    asm volatile("" ::: "memory");
    QUAD(1, 0);
    if (notlast) asm volatile("s_waitcnt vmcnt(4)" ::: "memory");
    else         asm volatile("s_waitcnt vmcnt(0)" ::: "memory");
    __builtin_amdgcn_s_barrier();
    asm volatile("" ::: "memory");

    // phase 3: Q(1,1) | stage A1'
    LOADB(1);
    if (notlast) stage(Ag, m0 + 128, k1, Lnxt + 16384);
    __builtin_amdgcn_s_barrier();
    asm volatile("" ::: "memory");
    QUAD(1, 1);
    __builtin_amdgcn_s_barrier();
    asm volatile("" ::: "memory");

    // phase 4: Q(0,1) | stage B1'
    LOADA(0);
    if (notlast) stage(Bg, n0 + 128, k1, Lnxt + 32768 + 16384);
    __builtin_amdgcn_s_barrier();
    asm volatile("" ::: "memory");
    QUAD(0, 1);
    if (notlast) asm volatile("s_waitcnt vmcnt(4)" ::: "memory");
    __builtin_amdgcn_s_barrier();
    asm volatile("" ::: "memory");
  }
#undef LOADA
#undef LOADB
#undef QUAD

  // epilogue
#pragma unroll
  for (int fm = 0; fm < 8; ++fm) {
    int row = m0 + wm * 128 + fm * 16 + hi * 4;
#pragma unroll
    for (int fn = 0; fn < 4; ++fn) {
      int col = n0 + wn * 64 + fn * 16 + l15;
#pragma unroll
      for (int j = 0; j < 4; ++j) {
        float v = acc[fm][fn][j];
        size_t off = (size_t)(row + j) * N + col;
        if (BIAS) v += bias[col];
        if (RELU) v = fmaxf(v, 0.f);
        if (OUTBF) ((__bf16*)Cm)[off] = (__bf16)v;
        else       ((float*)Cm)[off] = v;
      }
    }
  }
}

// ---------------- MFMA flash attention, paired q-tiles + split-KV ----------------
__global__ __launch_bounds__(512, 4) void attn_mfma(const __bf16* __restrict__ qkv,
    const __bf16* __restrict__ vt, __bf16* __restrict__ o) {
  __shared__ __align__(16) char smem[55296];
  __bf16 (*Ks)[64][72] = (__bf16 (*)[64][72])(smem);            // [2][64][72]
  __bf16 (*Vs)[64][72] = (__bf16 (*)[64][72])(smem + 18432);    // [2][64][72]
  __bf16 (*Ps)[16][72] = (__bf16 (*)[16][72])(smem + 36864);    // [8][16][72]
  float (*Os)[64]      = (float (*)[64])(smem);                 // merge overlay
  float* ms = (float*)(smem + 16384);
  float* ls = (float*)(smem + 16640);

  int bh = blockIdx.y;
  int b = bh >> 4, h = bh & 15;
  int bxA = blockIdx.x;        // 0..15
  int bxB = NT - 1 - bxA;      // 31..16
  int tid = threadIdx.x;
  int lane = tid & 63, w = tid >> 6;   // w 0..7
  int wq = w & 3;                      // q-row wave slot
  int g = w >> 2;                      // KV parity group
  int l15 = lane & 15, hi = lane >> 4;
  size_t bT = (size_t)b * TDIM;

  bf16x8 qfA[2], qfB[2];
  {
    const __bf16* qp = qkv + (bT + bxA * 64 + wq * 16 + l15) * QKVS + h * DHE;
    qfA[0] = *(const bf16x8*)(qp + hi * 8);
    qfA[1] = *(const bf16x8*)(qp + 32 + hi * 8);
    qp = qkv + (bT + bxB * 64 + wq * 16 + l15) * QKVS + h * DHE;
    qfB[0] = *(const bf16x8*)(qp + hi * 8);
    qfB[1] = *(const bf16x8*)(qp + 32 + hi * 8);
  }

  float mA[4], lA[4], mB[4], lB[4];
  f32x4 oA[4], oB[4];
#pragma unroll
  for (int r = 0; r < 4; ++r) {
    mA[r] = -INFINITY; lA[r] = 0.f; mB[r] = -INFINITY; lB[r] = 0.f;
    oA[r] = (f32x4){0.f, 0.f, 0.f, 0.f};
    oB[r] = (f32x4){0.f, 0.f, 0.f, 0.f};
  }

  int g_tid = tid & 255;
  int r0 = g_tid >> 3, c8 = (g_tid & 7) * 8;

  auto process = [&](const bf16x8* qf, float* m_i, float* l_i, f32x4* oacc,
                     int bx, int t2) {
    f32x4 sacc[4];
#pragma unroll
    for (int n = 0; n < 4; ++n) sacc[n] = (f32x4){0.f, 0.f, 0.f, 0.f};
    __builtin_amdgcn_s_setprio(1);
#pragma unroll
    for (int n = 0; n < 4; ++n)
#pragma unroll
      for (int kk = 0; kk < 2; ++kk) {
        bf16x8 kf = *(const bf16x8*)&Ks[g][n * 16 + l15][kk * 32 + hi * 8];
        sacc[n] = __builtin_amdgcn_mfma_f32_16x16x32_bf16(qf[kk], kf, sacc[n], 0, 0, 0);
      }
    __builtin_amdgcn_s_setprio(0);

    bool diag = (t2 == bx);
    float alpha[4];
#pragma unroll
    for (int r = 0; r < 4; ++r) {
      float s[4];
#pragma unroll
      for (int n = 0; n < 4; ++n) {
        float v = sacc[n][r] * 0.03125f;   // C^-0.5 = 1/32
        if (diag && (n * 16 + l15 > wq * 16 + hi * 4 + r)) v = -INFINITY;
        s[n] = v;
      }
      float mx = fmaxf(fmaxf(s[0], s[1]), fmaxf(s[2], s[3]));
#pragma unroll
      for (int off = 1; off < 16; off <<= 1) mx = fmaxf(mx, __shfl_xor(mx, off));
      float nm = fmaxf(m_i[r], mx);
      alpha[r] = __expf(m_i[r] - nm);
      m_i[r] = nm;
      float lsm = 0.f;
#pragma unroll
      for (int n = 0; n < 4; ++n) {
        float p = __expf(s[n] - nm);
        lsm += p;
        Ps[w][hi * 4 + r][n * 16 + l15] = (__bf16)p;
      }
#pragma unroll
      for (int off = 1; off < 16; off <<= 1) lsm += __shfl_xor(lsm, off);
      l_i[r] = l_i[r] * alpha[r] + lsm;
    }
#pragma unroll
    for (int n = 0; n < 4; ++n)
#pragma unroll
      for (int r = 0; r < 4; ++r) oacc[n][r] *= alpha[r];

    bf16x8 pa[2];
    pa[0] = *(const bf16x8*)&Ps[w][l15][hi * 8];
    pa[1] = *(const bf16x8*)&Ps[w][l15][32 + hi * 8];
    __builtin_amdgcn_s_setprio(1);
#pragma unroll
    for (int n = 0; n < 4; ++n)
#pragma unroll
      for (int kk = 0; kk < 2; ++kk) {
        bf16x8 vf = *(const bf16x8*)&Vs[g][n * 16 + l15][kk * 32 + hi * 8];
        oacc[n] = __builtin_amdgcn_mfma_f32_16x16x32_bf16(pa[kk], vf, oacc[n], 0, 0, 0);
      }
    __builtin_amdgcn_s_setprio(0);
  };

  for (int j = 0; j <= bxB / 2; ++j) {
    int t2 = 2 * j + g;
    bool have = (t2 <= bxB);
    __syncthreads();
    if (have) {
#pragma unroll
      for (int rr = 0; rr < 2; ++rr) {
        int row = rr * 32 + r0;
        *(bf16x8*)&Ks[g][row][c8] =
            *(const bf16x8*)(qkv + (bT + t2 * 64 + row) * QKVS + 1024 + h * DHE + c8);
        *(bf16x8*)&Vs[g][row][c8] =
            *(const bf16x8*)(vt + ((size_t)bh * 64 + row) * TDIM + t2 * 64 + c8);
      }
    }
    __syncthreads();
    if (t2 <= bxA) process(qfA, mA, lA, oA, bxA, t2);
    if (have)      process(qfB, mB, lB, oB, bxB, t2);
  }

  auto merge = [&](int bx, float* m_i, float* l_i, f32x4* oacc) {
    __syncthreads();
    if (g == 1) {
#pragma unroll
      for (int r = 0; r < 4; ++r) {
        int lrow = wq * 16 + hi * 4 + r;
        if (l15 == 0) { ms[lrow] = m_i[r]; ls[lrow] = l_i[r]; }
#pragma unroll
        for (int n = 0; n < 4; ++n)
          Os[lrow][n * 16 + l15] = oacc[n][r];
      }
    }
    __syncthreads();
    if (g == 0) {
#pragma unroll
      for (int r = 0; r < 4; ++r) {
        int lrow = wq * 16 + hi * 4 + r;
        float m1 = ms[lrow], l1 = ls[lrow];
        float mm = fmaxf(m_i[r], m1);
        float e0 = __expf(m_i[r] - mm), e1 = __expf(m1 - mm);
        float inv = 1.f / (l_i[r] * e0 + l1 * e1);
        size_t row = bT + bx * 64 + lrow;
#pragma unroll
        for (int n = 0; n < 4; ++n) {
          float v = (oacc[n][r] * e0 + Os[lrow][n * 16 + l15] * e1) * inv;
          o[row * CDIM + h * DHE + n * 16 + l15] = (__bf16)v;
        }
      }
    }
  };
  merge(bxA, mA, lA, oA);
  merge(bxB, mB, lB, oB);
}

// ---------------- launch ----------------
extern "C" void kernel_launch(void* const* d_in, const int* in_sizes, int n_in,
                              void* d_out, int out_size, void* d_ws, size_t ws_size,
                              hipStream_t stream) {
  (void)in_sizes; (void)n_in; (void)out_size; (void)ws_size;
  const float* x   = (const float*)d_in[0];
  const float* Wq  = (const float*)d_in[1];
  const float* Wk  = (const float*)d_in[2];
  const float* Wv  = (const float*)d_in[3];
  const float* Wo  = (const float*)d_in[4];
  const float* bo  = (const float*)d_in[5];
  const float* W1  = (const float*)d_in[6];
  const float* b1  = (const float*)d_in[7];
  const float* W2  = (const float*)d_in[8];
  const float* b2  = (const float*)d_in[9];
  const float* g1  = (const float*)d_in[10];
  const float* be1 = (const float*)d_in[11];
  const float* g2  = (const float*)d_in[12];
  const float* be2 = (const float*)d_in[13];
  float* out = (float*)d_out;

  char* wsb = (char*)d_ws;
  const size_t MB = 1024 * 1024;
  __bf16* Wqkvb = (__bf16*)(wsb + 0);
  __bf16* Wob   = (__bf16*)(wsb + 6  * MB);
  __bf16* W1b   = (__bf16*)(wsb + 8  * MB);
  __bf16* W2b   = (__bf16*)(wsb + 16 * MB);
  __bf16* qkvb  = (__bf16*)(wsb + 24 * MB);
  __bf16* hb    = (__bf16*)(wsb + 24 * MB);   // overlays qkvb+vt (dead by FFN)
  __bf16* vtb   = (__bf16*)(wsb + 48 * MB);
  __bf16* x1b   = (__bf16*)(wsb + 56 * MB);
  __bf16* attnb = (__bf16*)(wsb + 56 * MB);
  float*  xmid  = (float*) (wsb + 64 * MB);
  __bf16* x2b   = (__bf16*)(wsb + 80 * MB);
  float*  stats = (float*) (wsb + 88 * MB);
  float* sum1 = stats,        *sq1 = stats + 2048;
  float* sum2 = stats + 4096, *sq2 = stats + 6144;

  hipMemsetAsync(stats, 0, 4 * 2048 * sizeof(float), stream);

  pack_qkvT<<<dim3(32, 2, 48), 256, 0, stream>>>(Wq, Wk, Wv, Wqkvb);
  transp_bf16<<<dim3(32, 32),  256, 0, stream>>>(Wo, Wob, 1024, 1024);
  transp_bf16<<<dim3(128, 32), 256, 0, stream>>>(W1, W1b, 1024, 4096);
  transp_bf16<<<dim3(32, 128), 256, 0, stream>>>(W2, W2b, 4096, 1024);

  // LN1 -> x1b
  ln_stats<<<dim3(CDIM / 256, BDIM, 16), 256, 0, stream>>>(x, sum1, sq1);
  ln_apply<<<dim3((BDIM * TDIM * CDIM) / 256), 256, 0, stream>>>(x, sum1, sq1, g1, be1, x1b);

  // fused QKV projection (bf16 out): 256x256 pipelined GEMM, grid 12x16=192
  gemm256<false, false, true><<<192, 512, 0, stream>>>(
      x1b, Wqkvb, nullptr, qkvb, 4096, 3072, 1024, 12);

  // V transpose for PV operand
  transp_v<<<dim3(TDIM / 32, 64), 256, 0, stream>>>(qkvb, vtb);

  // MFMA flash attention (paired q-tiles, split-KV) -> attnb
  attn_mfma<<<dim3(NT / 2, BDIM * HDIM), 512, 0, stream>>>(qkvb, vtb, attnb);

  // output projection + residual (N=1024 -> keep 128x128 kernel)
  gemm_bf16<true, true, false, false><<<dim3(8, 32), 256, 0, stream>>>(
      attnb, Wob, bo, x, xmid, 4096, 1024, 1024);

  // LN2 -> x2b
  ln_stats<<<dim3(CDIM / 256, BDIM, 16), 256, 0, stream>>>(xmid, sum2, sq2);
  ln_apply<<<dim3((BDIM * TDIM * CDIM) / 256), 256, 0, stream>>>(xmid, sum2, sq2, g2, be2, x2b);

  // FFN1: 256x256 pipelined GEMM, grid 16x16=256
  gemm256<true, true, true><<<256, 512, 0, stream>>>(
      x2b, W1b, b1, hb, 4096, 4096, 1024, 16);
  // FFN2 (N=1024): 128x128 kernel
  gemm_bf16<true, true, false, false><<<dim3(8, 32), 256, 0, stream>>>(
      hb, W2b, b2, xmid, out, 4096, 1024, 4096);
}

// Round 6
// 295.134 us; speedup vs baseline: 6.8484x; 1.0585x over previous
//
#include <hip/hip_runtime.h>
#include <math.h>

// Transformer block. bf16 MFMA GEMMs + bf16 MFMA flash attention.
// R6: FFN2 moved to split-K=2 on the 256x256 pipelined GEMM + fp32 partial
// reduce (fused bias+residual). gemm256 gains ld (stride) + partial outputs.
// B=2 T=2048 C=1024 H=16 DH=64 F=4096. LN over TIME axis (ddof=1).
//
// Workspace (byte offsets):
//   [0,6M)     Wqkvb bf16 [3072][1024]  ([N][K])   } dead by FFN2 -> p0 fp32 [0,16M)
//   [6M,8M)    Wob   bf16 [1024][1024]             }
//   [8M,16M)   W1b   bf16 [4096][1024]             }
//   [16M,24M)  W2b   bf16 [1024][4096]
//   [24M,48M)  qkvb  bf16 [4096][3072]   \ overlaid by hb bf16 [4096][4096] ([24M,56M))
//   [48M,56M)  vt    bf16 [2048][2048]   /  vt dead after attn -> p1 fp32 [48M,64M)
//   [56M,64M)  x1b bf16, then attnb bf16 (dead after Wo-proj)
//   [64M,80M)  xmid fp32 [4096][1024]
//   [80M,88M)  x2b bf16
//   [88M,88M+32K) LN stats

#define TDIM 2048
#define BDIM 2
#define CDIM 1024
#define HDIM 16
#define DHE  64
#define QKVS 3072
#define NT   32          // T/64 q-tiles
#define LNEPS 1e-5f

typedef float f32x4 __attribute__((ext_vector_type(4)));
typedef __bf16 bf16x8 __attribute__((ext_vector_type(8)));

__device__ __forceinline__ void gld_lds16(const __bf16* g, __bf16* l) {
  __builtin_amdgcn_global_load_lds(
      (const __attribute__((address_space(1))) void*)g,
      (__attribute__((address_space(3))) void*)l, 16, 0, 0);
}

// ---------------- LayerNorm over T ----------------
__global__ __launch_bounds__(256) void ln_stats(const float* __restrict__ x,
                                                float* __restrict__ sumv,
                                                float* __restrict__ sqv) {
  int c = blockIdx.x * 256 + threadIdx.x;
  int b = blockIdx.y;
  int t0 = blockIdx.z * (TDIM / 16);
  const float* xp = x + ((size_t)b * TDIM + t0) * CDIM + c;
  float s = 0.f, q = 0.f;
  for (int t = 0; t < TDIM / 16; ++t) {
    float v = xp[(size_t)t * CDIM];
    s += v;
    q += v * v;
  }
  atomicAdd(&sumv[b * CDIM + c], s);
  atomicAdd(&sqv[b * CDIM + c], q);
}

__global__ __launch_bounds__(256) void ln_apply(const float* __restrict__ x,
    const float* __restrict__ sumv, const float* __restrict__ sqv,
    const float* __restrict__ gamma, const float* __restrict__ beta,
    __bf16* __restrict__ y) {
  size_t i = (size_t)blockIdx.x * 256 + threadIdx.x;
  int c = (int)(i & (CDIM - 1));
  int b = (int)(i >> 21);
  float mean = sumv[b * CDIM + c] * (1.f / TDIM);
  float var = (sqv[b * CDIM + c] - mean * mean * (float)TDIM) * (1.f / (TDIM - 1));
  float rstd = rsqrtf(var + LNEPS);
  y[i] = (__bf16)(gamma[c] * (x[i] - mean) * rstd + beta[c]);
}

// ---------------- weight repacks (transposed, bf16, [N][K]) ----------------
__global__ __launch_bounds__(256) void pack_qkvT(const float* __restrict__ Wq,
    const float* __restrict__ Wk, const float* __restrict__ Wv,
    __bf16* __restrict__ out) {
  __shared__ float tile[32][33];
  int mat = blockIdx.z >> 4, h = blockIdx.z & 15;
  const float* W = (mat == 0) ? Wq : (mat == 1) ? Wk : Wv;
  int c0 = blockIdx.x * 32, d0 = blockIdx.y * 32;
  int tx = threadIdx.x & 31, ty = threadIdx.x >> 5;
#pragma unroll
  for (int i = 0; i < 4; ++i)
    tile[ty + i * 8][tx] = W[((size_t)h * CDIM + c0 + ty + i * 8) * DHE + d0 + tx];
  __syncthreads();
#pragma unroll
  for (int i = 0; i < 4; ++i) {
    int n = mat * 1024 + h * 64 + d0 + ty + i * 8;
    out[(size_t)n * CDIM + c0 + tx] = (__bf16)tile[tx][ty + i * 8];
  }
}

__global__ __launch_bounds__(256) void transp_bf16(const float* __restrict__ in,
    __bf16* __restrict__ out, int R, int Cc) {
  __shared__ float tile[32][33];
  int c0 = blockIdx.x * 32, r0 = blockIdx.y * 32;
  int tx = threadIdx.x & 31, ty = threadIdx.x >> 5;
#pragma unroll
  for (int i = 0; i < 4; ++i)
    tile[ty + i * 8][tx] = in[(size_t)(r0 + ty + i * 8) * Cc + c0 + tx];
  __syncthreads();
#pragma unroll
  for (int i = 0; i < 4; ++i)
    out[(size_t)(c0 + ty + i * 8) * R + r0 + tx] = (__bf16)tile[tx][ty + i * 8];
}

// V part of qkvb -> vt[bh*64+d][t]
__global__ __launch_bounds__(256) void transp_v(const __bf16* __restrict__ qkv,
    __bf16* __restrict__ vtb) {
  __shared__ __bf16 tile[32][33];
  int bh = blockIdx.y >> 1, d0 = (blockIdx.y & 1) * 32;
  int b = bh >> 4, h = bh & 15;
  int t0 = blockIdx.x * 32;
  int tx = threadIdx.x & 31, ty = threadIdx.x >> 5;
#pragma unroll
  for (int i = 0; i < 4; ++i)
    tile[ty + i * 8][tx] = qkv[((size_t)b * TDIM + t0 + ty + i * 8) * QKVS + 2048 + h * DHE + d0 + tx];
  __syncthreads();
#pragma unroll
  for (int i = 0; i < 4; ++i)
    vtb[((size_t)bh * 64 + d0 + ty + i * 8) * TDIM + t0 + tx] = tile[tx][ty + i * 8];
}

// ---------------- 128x128 bf16 MFMA GEMM (kept for Wo projection) ----------------
template<bool BIAS, bool RES, bool RELU, bool OUTBF>
__global__ __launch_bounds__(256) void gemm_bf16(
    const __bf16* __restrict__ Ag, const __bf16* __restrict__ Bg,
    const float* __restrict__ bias, const float* __restrict__ res,
    void* __restrict__ Cm, int M, int N, int K) {
  __shared__ __bf16 As[128 * 32];
  __shared__ __bf16 Bs[128 * 32];
  int tid = threadIdx.x;
  int lane = tid & 63, wid = tid >> 6;
  int wr = wid >> 1, wc = wid & 1;
  int m0 = blockIdx.y * 128, n0 = blockIdx.x * 128;
  int srow = tid >> 2, scol = (tid & 3) * 8;
  int l15 = lane & 15, k8 = (lane >> 4) * 8;

  f32x4 acc[4][4];
#pragma unroll
  for (int m = 0; m < 4; ++m)
#pragma unroll
    for (int n = 0; n < 4; ++n) acc[m][n] = (f32x4){0.f, 0.f, 0.f, 0.f};

  for (int k0 = 0; k0 < K; k0 += 32) {
    __syncthreads();
    gld_lds16(Ag + (size_t)(m0 + srow) * K + k0 + scol,       As + tid * 8);
    gld_lds16(Ag + (size_t)(m0 + 64 + srow) * K + k0 + scol,  As + 2048 + tid * 8);
    gld_lds16(Bg + (size_t)(n0 + srow) * K + k0 + scol,       Bs + tid * 8);
    gld_lds16(Bg + (size_t)(n0 + 64 + srow) * K + k0 + scol,  Bs + 2048 + tid * 8);
    __syncthreads();

    bf16x8 af[4], bf[4];
#pragma unroll
    for (int m = 0; m < 4; ++m)
      af[m] = *(const bf16x8*)(As + (wr * 64 + m * 16 + l15) * 32 + k8);
#pragma unroll
    for (int n = 0; n < 4; ++n)
      bf[n] = *(const bf16x8*)(Bs + (wc * 64 + n * 16 + l15) * 32 + k8);
#pragma unroll
    for (int m = 0; m < 4; ++m)
#pragma unroll
      for (int n = 0; n < 4; ++n)
        acc[m][n] = __builtin_amdgcn_mfma_f32_16x16x32_bf16(af[m], bf[n], acc[m][n], 0, 0, 0);
  }

  int rbase = (lane >> 4) * 4;
#pragma unroll
  for (int m = 0; m < 4; ++m) {
    int row = m0 + wr * 64 + m * 16 + rbase;
#pragma unroll
    for (int n = 0; n < 4; ++n) {
      int col = n0 + wc * 64 + n * 16 + l15;
#pragma unroll
      for (int j = 0; j < 4; ++j) {
        float v = acc[m][n][j];
        size_t off = (size_t)(row + j) * N + col;
        if (BIAS) v += bias[col];
        if (RES)  v += res[off];
        if (RELU) v = fmaxf(v, 0.f);
        if (OUTBF) ((__bf16*)Cm)[off] = (__bf16)v;
        else       ((float*)Cm)[off] = v;
      }
    }
  }
}

// ---------------- 256x256 8-wave deep-pipelined GEMM ----------------
// C[M,N] = A[M,K'] @ Bt[N,K']^T restricted to K-chunk blockIdx.y (chunk len K,
// row stride ld). Partial fp32 output for chunk z goes to (z ? Cm2 : Cm).
// 4 phases/K-tile, Gray quadrant order; counted vmcnt; T2 LDS swizzle via
// pre-swizzled global source; T1 XCD block swizzle; T5 setprio.
template<bool BIAS, bool RELU, bool OUTBF>
__global__ __launch_bounds__(512, 2) void gemm256(
    const __bf16* __restrict__ Ag, const __bf16* __restrict__ Bg,
    const float* __restrict__ bias, void* __restrict__ Cm, void* __restrict__ Cm2,
    int M, int N, int K, int ld, int gnx) {
  __shared__ __align__(16) char lds[131072];
  int tid = threadIdx.x;
  int lane = tid & 63, wid = tid >> 6;
  int wm = wid >> 2, wn = wid & 3;
  int l15 = lane & 15, hi = lane >> 4;

  // split-K chunk offset
  size_t koff = (size_t)blockIdx.y * K;
  Ag += koff; Bg += koff;
  void* Cuse = blockIdx.y ? Cm2 : Cm;

  // T1: bijective XCD swizzle (m204)
  int nwg = gridDim.x;
  int q = nwg >> 3, r = nwg & 7;
  int xcd = blockIdx.x & 7, pos = blockIdx.x >> 3;
  int wgid = (xcd < r ? xcd * (q + 1) : r * (q + 1) + (xcd - r) * q) + pos;
  int m0 = (wgid / gnx) * 256, n0 = (wgid % gnx) * 256;

  int sr = tid >> 3;                       // staging row in 64-row call
  int skcol = ((tid & 7) ^ (sr & 7)) << 3; // pre-swizzled source k-col (elems)

  const int ac0 = (hi * 16) ^ ((l15 & 7) << 4);  // swizzled read col, kk=0
  const int ac1 = ac0 ^ 64;                      // kk=1

  f32x4 acc[8][4];
#pragma unroll
  for (int i = 0; i < 8; ++i)
#pragma unroll
    for (int j = 0; j < 4; ++j) acc[i][j] = (f32x4){0.f, 0.f, 0.f, 0.f};

  // stage one 128x64 half-tile (2 gload_lds per wave)
  auto stage = [&](const __bf16* __restrict__ G, int grow0, int k0, char* dst) {
#pragma unroll
    for (int c = 0; c < 2; ++c)
      gld_lds16(G + (size_t)(grow0 + c * 64 + sr) * ld + k0 + skcol,
                (__bf16*)(dst + c * 8192) + (size_t)tid * 8);
  };

  int KT = K >> 6;
  // prologue: K-tile 0 -> buf0, order A0,B0,A1,B1
  stage(Ag, m0,       0, lds);
  stage(Bg, n0,       0, lds + 32768);
  stage(Ag, m0 + 128, 0, lds + 16384);
  stage(Bg, n0 + 128, 0, lds + 32768 + 16384);
  asm volatile("s_waitcnt vmcnt(4)" ::: "memory");   // A0,B0 landed
  __builtin_amdgcn_s_barrier();
  asm volatile("" ::: "memory");

  bf16x8 a[4][2], b[2][2];

#define LOADA(MH) do { \
    const char* Ac_ = lds + (size_t)cur * 65536; \
    int rb_ = (wm * 128 + (MH) * 64 + l15) * 128; \
    _Pragma("unroll") \
    for (int i_ = 0; i_ < 4; ++i_) { \
      a[i_][0] = *(const bf16x8*)(Ac_ + rb_ + i_ * 2048 + ac0); \
      a[i_][1] = *(const bf16x8*)(Ac_ + rb_ + i_ * 2048 + ac1); \
    } } while (0)
#define LOADB(NH) do { \
    const char* Bc_ = lds + (size_t)cur * 65536 + 32768; \
    int rb_ = (wn * 64 + (NH) * 32 + l15) * 128; \
    _Pragma("unroll") \
    for (int j_ = 0; j_ < 2; ++j_) { \
      b[j_][0] = *(const bf16x8*)(Bc_ + rb_ + j_ * 2048 + ac0); \
      b[j_][1] = *(const bf16x8*)(Bc_ + rb_ + j_ * 2048 + ac1); \
    } } while (0)
#define QUAD(MH, NH) do { \
    __builtin_amdgcn_s_setprio(1); \
    _Pragma("unroll") \
    for (int i_ = 0; i_ < 4; ++i_) \
    _Pragma("unroll") \
    for (int j_ = 0; j_ < 2; ++j_) { \
      acc[(MH)*4+i_][(NH)*2+j_] = __builtin_amdgcn_mfma_f32_16x16x32_bf16( \
          a[i_][0], b[j_][0], acc[(MH)*4+i_][(NH)*2+j_], 0, 0, 0); \
      acc[(MH)*4+i_][(NH)*2+j_] = __builtin_amdgcn_mfma_f32_16x16x32_bf16( \
          a[i_][1], b[j_][1], acc[(MH)*4+i_][(NH)*2+j_], 0, 0, 0); \
    } \
    __builtin_amdgcn_s_setprio(0); } while (0)

  for (int kt = 0; kt < KT; ++kt) {
    int cur = kt & 1;
    char* Lnxt = lds + (size_t)(cur ^ 1) * 65536;
    int k1 = (kt + 1) << 6;
    bool notlast = (kt < KT - 1);

    // phase 1: Q(0,0) | stage A0'
    LOADA(0); LOADB(0);
    if (notlast) stage(Ag, m0, k1, Lnxt);
    __builtin_amdgcn_s_barrier();
    asm volatile("" ::: "memory");
    QUAD(0, 0);
    if (notlast) asm volatile("s_waitcnt vmcnt(4)" ::: "memory");
    else         asm volatile("s_waitcnt vmcnt(2)" ::: "memory");
    __builtin_amdgcn_s_barrier();
    asm volatile("" ::: "memory");

    // phase 2: Q(1,0) | stage B0'
    LOADA(1);
    if (notlast) stage(Bg, n0, k1, Lnxt + 32768);
    __builtin_amdgcn_s_barrier();
    asm volatile("" ::: "memory");
    QUAD(1, 0);
    if (notlast) asm volatile("s_waitcnt vmcnt(4)" ::: "memory");
    else         asm volatile("s_waitcnt vmcnt(0)" ::: "memory");
    __builtin_amdgcn_s_barrier();
    asm volatile("" ::: "memory");

    // phase 3: Q(1,1) | stage A1'
    LOADB(1);
    if (notlast) stage(Ag, m0 + 128, k1, Lnxt + 16384);
    __builtin_amdgcn_s_barrier();
    asm volatile("" ::: "memory");
    QUAD(1, 1);
    __builtin_amdgcn_s_barrier();
    asm volatile("" ::: "memory");

    // phase 4: Q(0,1) | stage B1'
    LOADA(0);
    if (notlast) stage(Bg, n0 + 128, k1, Lnxt + 32768 + 16384);
    __builtin_amdgcn_s_barrier();
    asm volatile("" ::: "memory");
    QUAD(0, 1);
    if (notlast) asm volatile("s_waitcnt vmcnt(4)" ::: "memory");
    __builtin_amdgcn_s_barrier();
    asm volatile("" ::: "memory");
  }
#undef LOADA
#undef LOADB
#undef QUAD

  // epilogue
#pragma unroll
  for (int fm = 0; fm < 8; ++fm) {
    int row = m0 + wm * 128 + fm * 16 + hi * 4;
#pragma unroll
    for (int fn = 0; fn < 4; ++fn) {
      int col = n0 + wn * 64 + fn * 16 + l15;
#pragma unroll
      for (int j = 0; j < 4; ++j) {
        float v = acc[fm][fn][j];
        size_t off = (size_t)(row + j) * N + col;
        if (BIAS) v += bias[col];
        if (RELU) v = fmaxf(v, 0.f);
        if (OUTBF) ((__bf16*)Cuse)[off] = (__bf16)v;
        else       ((float*)Cuse)[off] = v;
      }
    }
  }
}

// ---------------- split-K reduce: out = p0 + p1 + b2 + xmid (all fp32) ----------------
__global__ __launch_bounds__(256) void ffn2_reduce(const float* __restrict__ p0,
    const float* __restrict__ p1, const float* __restrict__ b2,
    const float* __restrict__ xmid, float* __restrict__ out) {
  size_t i = ((size_t)blockIdx.x * 256 + threadIdx.x) * 4;   // over 4M floats
  int c = (int)(i & (CDIM - 1));
  float4 a = *(const float4*)(p0 + i);
  float4 b = *(const float4*)(p1 + i);
  float4 r = *(const float4*)(xmid + i);
  float4 bb = *(const float4*)(b2 + c);
  float4 v;
  v.x = a.x + b.x + r.x + bb.x;
  v.y = a.y + b.y + r.y + bb.y;
  v.z = a.z + b.z + r.z + bb.z;
  v.w = a.w + b.w + r.w + bb.w;
  *(float4*)(out + i) = v;
}

// ---------------- MFMA flash attention, paired q-tiles + split-KV ----------------
__global__ __launch_bounds__(512, 4) void attn_mfma(const __bf16* __restrict__ qkv,
    const __bf16* __restrict__ vt, __bf16* __restrict__ o) {
  __shared__ __align__(16) char smem[55296];
  __bf16 (*Ks)[64][72] = (__bf16 (*)[64][72])(smem);            // [2][64][72]
  __bf16 (*Vs)[64][72] = (__bf16 (*)[64][72])(smem + 18432);    // [2][64][72]
  __bf16 (*Ps)[16][72] = (__bf16 (*)[16][72])(smem + 36864);    // [8][16][72]
  float (*Os)[64]      = (float (*)[64])(smem);                 // merge overlay
  float* ms = (float*)(smem + 16384);
  float* ls = (float*)(smem + 16640);

  int bh = blockIdx.y;
  int b = bh >> 4, h = bh & 15;
  int bxA = blockIdx.x;        // 0..15
  int bxB = NT - 1 - bxA;      // 31..16
  int tid = threadIdx.x;
  int lane = tid & 63, w = tid >> 6;   // w 0..7
  int wq = w & 3;                      // q-row wave slot
  int g = w >> 2;                      // KV parity group
  int l15 = lane & 15, hi = lane >> 4;
  size_t bT = (size_t)b * TDIM;

  bf16x8 qfA[2], qfB[2];
  {
    const __bf16* qp = qkv + (bT + bxA * 64 + wq * 16 + l15) * QKVS + h * DHE;
    qfA[0] = *(const bf16x8*)(qp + hi * 8);
    qfA[1] = *(const bf16x8*)(qp + 32 + hi * 8);
    qp = qkv + (bT + bxB * 64 + wq * 16 + l15) * QKVS + h * DHE;
    qfB[0] = *(const bf16x8*)(qp + hi * 8);
    qfB[1] = *(const bf16x8*)(qp + 32 + hi * 8);
  }

  float mA[4], lA[4], mB[4], lB[4];
  f32x4 oA[4], oB[4];
#pragma unroll
  for (int r = 0; r < 4; ++r) {
    mA[r] = -INFINITY; lA[r] = 0.f; mB[r] = -INFINITY; lB[r] = 0.f;
    oA[r] = (f32x4){0.f, 0.f, 0.f, 0.f};
    oB[r] = (f32x4){0.f, 0.f, 0.f, 0.f};
  }

  int g_tid = tid & 255;
  int r0 = g_tid >> 3, c8 = (g_tid & 7) * 8;

  auto process = [&](const bf16x8* qf, float* m_i, float* l_i, f32x4* oacc,
                     int bx, int t2) {
    f32x4 sacc[4];
#pragma unroll
    for (int n = 0; n < 4; ++n) sacc[n] = (f32x4){0.f, 0.f, 0.f, 0.f};
    __builtin_amdgcn_s_setprio(1);
#pragma unroll
    for (int n = 0; n < 4; ++n)
#pragma unroll
      for (int kk = 0; kk < 2; ++kk) {
        bf16x8 kf = *(const bf16x8*)&Ks[g][n * 16 + l15][kk * 32 + hi * 8];
        sacc[n] = __builtin_amdgcn_mfma_f32_16x16x32_bf16(qf[kk], kf, sacc[n], 0, 0, 0);
      }
    __builtin_amdgcn_s_setprio(0);

    bool diag = (t2 == bx);
    float alpha[4];
#pragma unroll
    for (int r = 0; r < 4; ++r) {
      float s[4];
#pragma unroll
      for (int n = 0; n < 4; ++n) {
        float v = sacc[n][r] * 0.03125f;   // C^-0.5 = 1/32
        if (diag && (n * 16 + l15 > wq * 16 + hi * 4 + r)) v = -INFINITY;
        s[n] = v;
      }
      float mx = fmaxf(fmaxf(s[0], s[1]), fmaxf(s[2], s[3]));
#pragma unroll
      for (int off = 1; off < 16; off <<= 1) mx = fmaxf(mx, __shfl_xor(mx, off));
      float nm = fmaxf(m_i[r], mx);
      alpha[r] = __expf(m_i[r] - nm);
      m_i[r] = nm;
      float lsm = 0.f;
#pragma unroll
      for (int n = 0; n < 4; ++n) {
        float p = __expf(s[n] - nm);
        lsm += p;
        Ps[w][hi * 4 + r][n * 16 + l15] = (__bf16)p;
      }
#pragma unroll
      for (int off = 1; off < 16; off <<= 1) lsm += __shfl_xor(lsm, off);
      l_i[r] = l_i[r] * alpha[r] + lsm;
    }
#pragma unroll
    for (int n = 0; n < 4; ++n)
#pragma unroll
      for (int r = 0; r < 4; ++r) oacc[n][r] *= alpha[r];

    bf16x8 pa[2];
    pa[0] = *(const bf16x8*)&Ps[w][l15][hi * 8];
    pa[1] = *(const bf16x8*)&Ps[w][l15][32 + hi * 8];
    __builtin_amdgcn_s_setprio(1);
#pragma unroll
    for (int n = 0; n < 4; ++n)
#pragma unroll
      for (int kk = 0; kk < 2; ++kk) {
        bf16x8 vf = *(const bf16x8*)&Vs[g][n * 16 + l15][kk * 32 + hi * 8];
        oacc[n] = __builtin_amdgcn_mfma_f32_16x16x32_bf16(pa[kk], vf, oacc[n], 0, 0, 0);
      }
    __builtin_amdgcn_s_setprio(0);
  };

  for (int j = 0; j <= bxB / 2; ++j) {
    int t2 = 2 * j + g;
    bool have = (t2 <= bxB);
    __syncthreads();
    if (have) {
#pragma unroll
      for (int rr = 0; rr < 2; ++rr) {
        int row = rr * 32 + r0;
        *(bf16x8*)&Ks[g][row][c8] =
            *(const bf16x8*)(qkv + (bT + t2 * 64 + row) * QKVS + 1024 + h * DHE + c8);
        *(bf16x8*)&Vs[g][row][c8] =
            *(const bf16x8*)(vt + ((size_t)bh * 64 + row) * TDIM + t2 * 64 + c8);
      }
    }
    __syncthreads();
    if (t2 <= bxA) process(qfA, mA, lA, oA, bxA, t2);
    if (have)      process(qfB, mB, lB, oB, bxB, t2);
  }

  auto merge = [&](int bx, float* m_i, float* l_i, f32x4* oacc) {
    __syncthreads();
    if (g == 1) {
#pragma unroll
      for (int r = 0; r < 4; ++r) {
        int lrow = wq * 16 + hi * 4 + r;
        if (l15 == 0) { ms[lrow] = m_i[r]; ls[lrow] = l_i[r]; }
#pragma unroll
        for (int n = 0; n < 4; ++n)
          Os[lrow][n * 16 + l15] = oacc[n][r];
      }
    }
    __syncthreads();
    if (g == 0) {
#pragma unroll
      for (int r = 0; r < 4; ++r) {
        int lrow = wq * 16 + hi * 4 + r;
        float m1 = ms[lrow], l1 = ls[lrow];
        float mm = fmaxf(m_i[r], m1);
        float e0 = __expf(m_i[r] - mm), e1 = __expf(m1 - mm);
        float inv = 1.f / (l_i[r] * e0 + l1 * e1);
        size_t row = bT + bx * 64 + lrow;
#pragma unroll
        for (int n = 0; n < 4; ++n) {
          float v = (oacc[n][r] * e0 + Os[lrow][n * 16 + l15] * e1) * inv;
          o[row * CDIM + h * DHE + n * 16 + l15] = (__bf16)v;
        }
      }
    }
  };
  merge(bxA, mA, lA, oA);
  merge(bxB, mB, lB, oB);
}

// ---------------- launch ----------------
extern "C" void kernel_launch(void* const* d_in, const int* in_sizes, int n_in,
                              void* d_out, int out_size, void* d_ws, size_t ws_size,
                              hipStream_t stream) {
  (void)in_sizes; (void)n_in; (void)out_size; (void)ws_size;
  const float* x   = (const float*)d_in[0];
  const float* Wq  = (const float*)d_in[1];
  const float* Wk  = (const float*)d_in[2];
  const float* Wv  = (const float*)d_in[3];
  const float* Wo  = (const float*)d_in[4];
  const float* bo  = (const float*)d_in[5];
  const float* W1  = (const float*)d_in[6];
  const float* b1  = (const float*)d_in[7];
  const float* W2  = (const float*)d_in[8];
  const float* b2  = (const float*)d_in[9];
  const float* g1  = (const float*)d_in[10];
  const float* be1 = (const float*)d_in[11];
  const float* g2  = (const float*)d_in[12];
  const float* be2 = (const float*)d_in[13];
  float* out = (float*)d_out;

  char* wsb = (char*)d_ws;
  const size_t MB = 1024 * 1024;
  __bf16* Wqkvb = (__bf16*)(wsb + 0);
  __bf16* Wob   = (__bf16*)(wsb + 6  * MB);
  __bf16* W1b   = (__bf16*)(wsb + 8  * MB);
  __bf16* W2b   = (__bf16*)(wsb + 16 * MB);
  __bf16* qkvb  = (__bf16*)(wsb + 24 * MB);
  __bf16* hb    = (__bf16*)(wsb + 24 * MB);   // overlays qkvb+vt (dead by FFN)
  __bf16* vtb   = (__bf16*)(wsb + 48 * MB);
  __bf16* x1b   = (__bf16*)(wsb + 56 * MB);
  __bf16* attnb = (__bf16*)(wsb + 56 * MB);
  float*  xmid  = (float*) (wsb + 64 * MB);
  __bf16* x2b   = (__bf16*)(wsb + 80 * MB);
  float*  stats = (float*) (wsb + 88 * MB);
  float*  p0    = (float*) (wsb + 0);         // FFN2 partial 0 (over dead weights)
  float*  p1    = (float*) (wsb + 48 * MB);   // FFN2 partial 1 (over dead vt/x1b)
  float* sum1 = stats,        *sq1 = stats + 2048;
  float* sum2 = stats + 4096, *sq2 = stats + 6144;

  hipMemsetAsync(stats, 0, 4 * 2048 * sizeof(float), stream);

  pack_qkvT<<<dim3(32, 2, 48), 256, 0, stream>>>(Wq, Wk, Wv, Wqkvb);
  transp_bf16<<<dim3(32, 32),  256, 0, stream>>>(Wo, Wob, 1024, 1024);
  transp_bf16<<<dim3(128, 32), 256, 0, stream>>>(W1, W1b, 1024, 4096);
  transp_bf16<<<dim3(32, 128), 256, 0, stream>>>(W2, W2b, 4096, 1024);

  // LN1 -> x1b
  ln_stats<<<dim3(CDIM / 256, BDIM, 16), 256, 0, stream>>>(x, sum1, sq1);
  ln_apply<<<dim3((BDIM * TDIM * CDIM) / 256), 256, 0, stream>>>(x, sum1, sq1, g1, be1, x1b);

  // fused QKV projection (bf16 out): 256x256 pipelined GEMM, grid 12x16=192
  gemm256<false, false, true><<<dim3(192, 1), 512, 0, stream>>>(
      x1b, Wqkvb, nullptr, qkvb, qkvb, 4096, 3072, 1024, 1024, 12);

  // V transpose for PV operand
  transp_v<<<dim3(TDIM / 32, 64), 256, 0, stream>>>(qkvb, vtb);

  // MFMA flash attention (paired q-tiles, split-KV) -> attnb
  attn_mfma<<<dim3(NT / 2, BDIM * HDIM), 512, 0, stream>>>(qkvb, vtb, attnb);

  // output projection + residual (N=1024 -> 128x128 kernel)
  gemm_bf16<true, true, false, false><<<dim3(8, 32), 256, 0, stream>>>(
      attnb, Wob, bo, x, xmid, 4096, 1024, 1024);

  // LN2 -> x2b
  ln_stats<<<dim3(CDIM / 256, BDIM, 16), 256, 0, stream>>>(xmid, sum2, sq2);
  ln_apply<<<dim3((BDIM * TDIM * CDIM) / 256), 256, 0, stream>>>(xmid, sum2, sq2, g2, be2, x2b);

  // FFN1: 256x256 pipelined GEMM, grid 16x16=256
  gemm256<true, true, true><<<dim3(256, 1), 512, 0, stream>>>(
      x2b, W1b, b1, hb, hb, 4096, 4096, 1024, 1024, 16);

  // FFN2: split-K=2 on 256x256 GEMM -> fp32 partials, then fused reduce
  gemm256<false, false, false><<<dim3(64, 2), 512, 0, stream>>>(
      hb, W2b, nullptr, p0, p1, 4096, 1024, 2048, 4096, 4);
  ffn2_reduce<<<dim3(4096), 256, 0, stream>>>(p0, p1, b2, xmid, out);
}

// Round 7
// 272.954 us; speedup vs baseline: 7.4049x; 1.0813x over previous
//
#include <hip/hip_runtime.h>
#include <math.h>

// Transformer block. bf16 MFMA GEMMs + bf16 MFMA flash attention.
// R7: attention softmax restructured — swapped QK^T (lane-local rows),
// in-lane max reduce, l tracked via ones-column MFMA, defer-max (THR=8 in
// log2 domain), exp2-domain softmax, vector P-writes. Weight packs fused.
// B=2 T=2048 C=1024 H=16 DH=64 F=4096. LN over TIME axis (ddof=1).
//
// Workspace (byte offsets):
//   [0,6M)     Wqkvb bf16 [3072][1024]  ([N][K])   } dead by FFN2 -> p0 fp32 [0,16M)
//   [6M,8M)    Wob   bf16 [1024][1024]             }
//   [8M,16M)   W1b   bf16 [4096][1024]             }
//   [16M,24M)  W2b   bf16 [1024][4096]
//   [24M,48M)  qkvb  bf16 [4096][3072]   \ overlaid by hb bf16 [4096][4096] ([24M,56M))
//   [48M,56M)  vt    bf16 [2048][2048]   /  vt dead after attn -> p1 fp32 [48M,64M)
//   [56M,64M)  x1b bf16, then attnb bf16 (dead after Wo-proj)
//   [64M,80M)  xmid fp32 [4096][1024]
//   [80M,88M)  x2b bf16
//   [88M,88M+32K) LN stats

#define TDIM 2048
#define BDIM 2
#define CDIM 1024
#define HDIM 16
#define DHE  64
#define QKVS 3072
#define NT   32          // T/64 q-tiles
#define LNEPS 1e-5f
#define SC2  0.0450842200278f   // (1/32) * log2(e)

typedef float f32x4 __attribute__((ext_vector_type(4)));
typedef __bf16 bf16x8 __attribute__((ext_vector_type(8)));
typedef __bf16 bf16x4 __attribute__((ext_vector_type(4)));

__device__ __forceinline__ void gld_lds16(const __bf16* g, __bf16* l) {
  __builtin_amdgcn_global_load_lds(
      (const __attribute__((address_space(1))) void*)g,
      (__attribute__((address_space(3))) void*)l, 16, 0, 0);
}

// ---------------- LayerNorm over T ----------------
__global__ __launch_bounds__(256) void ln_stats(const float* __restrict__ x,
                                                float* __restrict__ sumv,
                                                float* __restrict__ sqv) {
  int c = blockIdx.x * 256 + threadIdx.x;
  int b = blockIdx.y;
  int t0 = blockIdx.z * (TDIM / 16);
  const float* xp = x + ((size_t)b * TDIM + t0) * CDIM + c;
  float s = 0.f, q = 0.f;
  for (int t = 0; t < TDIM / 16; ++t) {
    float v = xp[(size_t)t * CDIM];
    s += v;
    q += v * v;
  }
  atomicAdd(&sumv[b * CDIM + c], s);
  atomicAdd(&sqv[b * CDIM + c], q);
}

__global__ __launch_bounds__(256) void ln_apply(const float* __restrict__ x,
    const float* __restrict__ sumv, const float* __restrict__ sqv,
    const float* __restrict__ gamma, const float* __restrict__ beta,
    __bf16* __restrict__ y) {
  size_t i = (size_t)blockIdx.x * 256 + threadIdx.x;
  int c = (int)(i & (CDIM - 1));
  int b = (int)(i >> 21);
  float mean = sumv[b * CDIM + c] * (1.f / TDIM);
  float var = (sqv[b * CDIM + c] - mean * mean * (float)TDIM) * (1.f / (TDIM - 1));
  float rstd = rsqrtf(var + LNEPS);
  y[i] = (__bf16)(gamma[c] * (x[i] - mean) * rstd + beta[c]);
}

// ---------------- fused weight repack (all four, one launch) ----------------
// t < 3072: Wq/Wk/Wv [H,C,DH] -> Wqkvb [3072][1024]
// 3072..4095: Wo [1024][1024] -> Wob^T; 4096..8191: W1 [1024][4096] -> W1b^T;
// 8192..12287: W2 [4096][1024] -> W2b^T.
__global__ __launch_bounds__(256) void pack_all(
    const float* __restrict__ Wq, const float* __restrict__ Wk,
    const float* __restrict__ Wv, const float* __restrict__ Wo,
    const float* __restrict__ W1, const float* __restrict__ W2,
    __bf16* __restrict__ Wqkvb, __bf16* __restrict__ Wob,
    __bf16* __restrict__ W1b, __bf16* __restrict__ W2b) {
  __shared__ float tile[32][33];
  int t = blockIdx.x;
  int tx = threadIdx.x & 31, ty = threadIdx.x >> 5;
  if (t < 3072) {
    int mat = t >> 10, rem = t & 1023;
    int h = rem >> 6, rr = rem & 63;
    int c0 = (rr & 31) * 32, d0 = (rr >> 5) * 32;
    const float* W = (mat == 0) ? Wq : (mat == 1) ? Wk : Wv;
#pragma unroll
    for (int i = 0; i < 4; ++i)
      tile[ty + i * 8][tx] = W[((size_t)h * CDIM + c0 + ty + i * 8) * DHE + d0 + tx];
    __syncthreads();
#pragma unroll
    for (int i = 0; i < 4; ++i) {
      int n = mat * 1024 + h * 64 + d0 + ty + i * 8;
      Wqkvb[(size_t)n * CDIM + c0 + tx] = (__bf16)tile[tx][ty + i * 8];
    }
  } else {
    const float* in; __bf16* outp; int Cc, R, l;
    if (t < 4096)      { in = Wo; outp = Wob; R = 1024; Cc = 1024; l = t - 3072; }
    else if (t < 8192) { in = W1; outp = W1b; R = 1024; Cc = 4096; l = t - 4096; }
    else               { in = W2; outp = W2b; R = 4096; Cc = 1024; l = t - 8192; }
    int ncx = Cc >> 5;
    int c0 = (l % ncx) * 32, r0 = (l / ncx) * 32;
#pragma unroll
    for (int i = 0; i < 4; ++i)
      tile[ty + i * 8][tx] = in[(size_t)(r0 + ty + i * 8) * Cc + c0 + tx];
    __syncthreads();
#pragma unroll
    for (int i = 0; i < 4; ++i)
      outp[(size_t)(c0 + ty + i * 8) * R + r0 + tx] = (__bf16)tile[tx][ty + i * 8];
  }
}

// V part of qkvb -> vt[bh*64+d][t]
__global__ __launch_bounds__(256) void transp_v(const __bf16* __restrict__ qkv,
    __bf16* __restrict__ vtb) {
  __shared__ __bf16 tile[32][33];
  int bh = blockIdx.y >> 1, d0 = (blockIdx.y & 1) * 32;
  int b = bh >> 4, h = bh & 15;
  int t0 = blockIdx.x * 32;
  int tx = threadIdx.x & 31, ty = threadIdx.x >> 5;
#pragma unroll
  for (int i = 0; i < 4; ++i)
    tile[ty + i * 8][tx] = qkv[((size_t)b * TDIM + t0 + ty + i * 8) * QKVS + 2048 + h * DHE + d0 + tx];
  __syncthreads();
#pragma unroll
  for (int i = 0; i < 4; ++i)
    vtb[((size_t)bh * 64 + d0 + ty + i * 8) * TDIM + t0 + tx] = tile[tx][ty + i * 8];
}

// ---------------- 128x128 bf16 MFMA GEMM (kept for Wo projection) ----------------
template<bool BIAS, bool RES, bool RELU, bool OUTBF>
__global__ __launch_bounds__(256) void gemm_bf16(
    const __bf16* __restrict__ Ag, const __bf16* __restrict__ Bg,
    const float* __restrict__ bias, const float* __restrict__ res,
    void* __restrict__ Cm, int M, int N, int K) {
  __shared__ __bf16 As[128 * 32];
  __shared__ __bf16 Bs[128 * 32];
  int tid = threadIdx.x;
  int lane = tid & 63, wid = tid >> 6;
  int wr = wid >> 1, wc = wid & 1;
  int m0 = blockIdx.y * 128, n0 = blockIdx.x * 128;
  int srow = tid >> 2, scol = (tid & 3) * 8;
  int l15 = lane & 15, k8 = (lane >> 4) * 8;

  f32x4 acc[4][4];
#pragma unroll
  for (int m = 0; m < 4; ++m)
#pragma unroll
    for (int n = 0; n < 4; ++n) acc[m][n] = (f32x4){0.f, 0.f, 0.f, 0.f};

  for (int k0 = 0; k0 < K; k0 += 32) {
    __syncthreads();
    gld_lds16(Ag + (size_t)(m0 + srow) * K + k0 + scol,       As + tid * 8);
    gld_lds16(Ag + (size_t)(m0 + 64 + srow) * K + k0 + scol,  As + 2048 + tid * 8);
    gld_lds16(Bg + (size_t)(n0 + srow) * K + k0 + scol,       Bs + tid * 8);
    gld_lds16(Bg + (size_t)(n0 + 64 + srow) * K + k0 + scol,  Bs + 2048 + tid * 8);
    __syncthreads();

    bf16x8 af[4], bf[4];
#pragma unroll
    for (int m = 0; m < 4; ++m)
      af[m] = *(const bf16x8*)(As + (wr * 64 + m * 16 + l15) * 32 + k8);
#pragma unroll
    for (int n = 0; n < 4; ++n)
      bf[n] = *(const bf16x8*)(Bs + (wc * 64 + n * 16 + l15) * 32 + k8);
#pragma unroll
    for (int m = 0; m < 4; ++m)
#pragma unroll
      for (int n = 0; n < 4; ++n)
        acc[m][n] = __builtin_amdgcn_mfma_f32_16x16x32_bf16(af[m], bf[n], acc[m][n], 0, 0, 0);
  }

  int rbase = (lane >> 4) * 4;
#pragma unroll
  for (int m = 0; m < 4; ++m) {
    int row = m0 + wr * 64 + m * 16 + rbase;
#pragma unroll
    for (int n = 0; n < 4; ++n) {
      int col = n0 + wc * 64 + n * 16 + l15;
#pragma unroll
      for (int j = 0; j < 4; ++j) {
        float v = acc[m][n][j];
        size_t off = (size_t)(row + j) * N + col;
        if (BIAS) v += bias[col];
        if (RES)  v += res[off];
        if (RELU) v = fmaxf(v, 0.f);
        if (OUTBF) ((__bf16*)Cm)[off] = (__bf16)v;
        else       ((float*)Cm)[off] = v;
      }
    }
  }
}

// ---------------- 256x256 8-wave deep-pipelined GEMM ----------------
template<bool BIAS, bool RELU, bool OUTBF>
__global__ __launch_bounds__(512, 2) void gemm256(
    const __bf16* __restrict__ Ag, const __bf16* __restrict__ Bg,
    const float* __restrict__ bias, void* __restrict__ Cm, void* __restrict__ Cm2,
    int M, int N, int K, int ld, int gnx) {
  __shared__ __align__(16) char lds[131072];
  int tid = threadIdx.x;
  int lane = tid & 63, wid = tid >> 6;
  int wm = wid >> 2, wn = wid & 3;
  int l15 = lane & 15, hi = lane >> 4;

  size_t koff = (size_t)blockIdx.y * K;
  Ag += koff; Bg += koff;
  void* Cuse = blockIdx.y ? Cm2 : Cm;

  int nwg = gridDim.x;
  int q = nwg >> 3, r = nwg & 7;
  int xcd = blockIdx.x & 7, pos = blockIdx.x >> 3;
  int wgid = (xcd < r ? xcd * (q + 1) : r * (q + 1) + (xcd - r) * q) + pos;
  int m0 = (wgid / gnx) * 256, n0 = (wgid % gnx) * 256;

  int sr = tid >> 3;
  int skcol = ((tid & 7) ^ (sr & 7)) << 3;

  const int ac0 = (hi * 16) ^ ((l15 & 7) << 4);
  const int ac1 = ac0 ^ 64;

  f32x4 acc[8][4];
#pragma unroll
  for (int i = 0; i < 8; ++i)
#pragma unroll
    for (int j = 0; j < 4; ++j) acc[i][j] = (f32x4){0.f, 0.f, 0.f, 0.f};

  auto stage = [&](const __bf16* __restrict__ G, int grow0, int k0, char* dst) {
#pragma unroll
    for (int c = 0; c < 2; ++c)
      gld_lds16(G + (size_t)(grow0 + c * 64 + sr) * ld + k0 + skcol,
                (__bf16*)(dst + c * 8192) + (size_t)tid * 8);
  };

  int KT = K >> 6;
  stage(Ag, m0,       0, lds);
  stage(Bg, n0,       0, lds + 32768);
  stage(Ag, m0 + 128, 0, lds + 16384);
  stage(Bg, n0 + 128, 0, lds + 32768 + 16384);
  asm volatile("s_waitcnt vmcnt(4)" ::: "memory");
  __builtin_amdgcn_s_barrier();
  asm volatile("" ::: "memory");

  bf16x8 a[4][2], b[2][2];

#define LOADA(MH) do { \
    const char* Ac_ = lds + (size_t)cur * 65536; \
    int rb_ = (wm * 128 + (MH) * 64 + l15) * 128; \
    _Pragma("unroll") \
    for (int i_ = 0; i_ < 4; ++i_) { \
      a[i_][0] = *(const bf16x8*)(Ac_ + rb_ + i_ * 2048 + ac0); \
      a[i_][1] = *(const bf16x8*)(Ac_ + rb_ + i_ * 2048 + ac1); \
    } } while (0)
#define LOADB(NH) do { \
    const char* Bc_ = lds + (size_t)cur * 65536 + 32768; \
    int rb_ = (wn * 64 + (NH) * 32 + l15) * 128; \
    _Pragma("unroll") \
    for (int j_ = 0; j_ < 2; ++j_) { \
      b[j_][0] = *(const bf16x8*)(Bc_ + rb_ + j_ * 2048 + ac0); \
      b[j_][1] = *(const bf16x8*)(Bc_ + rb_ + j_ * 2048 + ac1); \
    } } while (0)
#define QUAD(MH, NH) do { \
    __builtin_amdgcn_s_setprio(1); \
    _Pragma("unroll") \
    for (int i_ = 0; i_ < 4; ++i_) \
    _Pragma("unroll") \
    for (int j_ = 0; j_ < 2; ++j_) { \
      acc[(MH)*4+i_][(NH)*2+j_] = __builtin_amdgcn_mfma_f32_16x16x32_bf16( \
          a[i_][0], b[j_][0], acc[(MH)*4+i_][(NH)*2+j_], 0, 0, 0); \
      acc[(MH)*4+i_][(NH)*2+j_] = __builtin_amdgcn_mfma_f32_16x16x32_bf16( \
          a[i_][1], b[j_][1], acc[(MH)*4+i_][(NH)*2+j_], 0, 0, 0); \
    } \
    __builtin_amdgcn_s_setprio(0); } while (0)

  for (int kt = 0; kt < KT; ++kt) {
    int cur = kt & 1;
    char* Lnxt = lds + (size_t)(cur ^ 1) * 65536;
    int k1 = (kt + 1) << 6;
    bool notlast = (kt < KT - 1);

    LOADA(0); LOADB(0);
    if (notlast) stage(Ag, m0, k1, Lnxt);
    __builtin_amdgcn_s_barrier();
    asm volatile("" ::: "memory");
    QUAD(0, 0);
    if (notlast) asm volatile("s_waitcnt vmcnt(4)" ::: "memory");
    else         asm volatile("s_waitcnt vmcnt(2)" ::: "memory");
    __builtin_amdgcn_s_barrier();
    asm volatile("" ::: "memory");

    LOADA(1);
    if (notlast) stage(Bg, n0, k1, Lnxt + 32768);
    __builtin_amdgcn_s_barrier();
    asm volatile("" ::: "memory");
    QUAD(1, 0);
    if (notlast) asm volatile("s_waitcnt vmcnt(4)" ::: "memory");
    else         asm volatile("s_waitcnt vmcnt(0)" ::: "memory");
    __builtin_amdgcn_s_barrier();
    asm volatile("" ::: "memory");

    LOADB(1);
    if (notlast) stage(Ag, m0 + 128, k1, Lnxt + 16384);
    __builtin_amdgcn_s_barrier();
    asm volatile("" ::: "memory");
    QUAD(1, 1);
    __builtin_amdgcn_s_barrier();
    asm volatile("" ::: "memory");

    LOADA(0);
    if (notlast) stage(Bg, n0 + 128, k1, Lnxt + 32768 + 16384);
    __builtin_amdgcn_s_barrier();
    asm volatile("" ::: "memory");
    QUAD(0, 1);
    if (notlast) asm volatile("s_waitcnt vmcnt(4)" ::: "memory");
    __builtin_amdgcn_s_barrier();
    asm volatile("" ::: "memory");
  }
#undef LOADA
#undef LOADB
#undef QUAD

#pragma unroll
  for (int fm = 0; fm < 8; ++fm) {
    int row = m0 + wm * 128 + fm * 16 + hi * 4;
#pragma unroll
    for (int fn = 0; fn < 4; ++fn) {
      int col = n0 + wn * 64 + fn * 16 + l15;
#pragma unroll
      for (int j = 0; j < 4; ++j) {
        float v = acc[fm][fn][j];
        size_t off = (size_t)(row + j) * N + col;
        if (BIAS) v += bias[col];
        if (RELU) v = fmaxf(v, 0.f);
        if (OUTBF) ((__bf16*)Cuse)[off] = (__bf16)v;
        else       ((float*)Cuse)[off] = v;
      }
    }
  }
}

// ---------------- split-K reduce: out = p0 + p1 + b2 + xmid (all fp32) ----------------
__global__ __launch_bounds__(256) void ffn2_reduce(const float* __restrict__ p0,
    const float* __restrict__ p1, const float* __restrict__ b2,
    const float* __restrict__ xmid, float* __restrict__ out) {
  size_t i = ((size_t)blockIdx.x * 256 + threadIdx.x) * 4;
  int c = (int)(i & (CDIM - 1));
  float4 a = *(const float4*)(p0 + i);
  float4 b = *(const float4*)(p1 + i);
  float4 r = *(const float4*)(xmid + i);
  float4 bb = *(const float4*)(b2 + c);
  float4 v;
  v.x = a.x + b.x + r.x + bb.x;
  v.y = a.y + b.y + r.y + bb.y;
  v.z = a.z + b.z + r.z + bb.z;
  v.w = a.w + b.w + r.w + bb.w;
  *(float4*)(out + i) = v;
}

// ---------------- MFMA flash attention (R7 softmax restructure) ----------------
// Swapped QK^T: sacc[n] = mfma(K_frag, Q_frag) -> lane (l15,hi) holds
// S[tk=n*16+hi*4+j][tq=l15] (16 values of q-row l15). Softmax per-row is
// in-lane + 2 shfl_xor. l tracked via ones-column MFMA (lanes l15==0).
// Defer-max: skip O/l rescale unless any row grew by >8 (log2 units).
__global__ __launch_bounds__(512, 4) void attn_mfma(const __bf16* __restrict__ qkv,
    const __bf16* __restrict__ vt, __bf16* __restrict__ o) {
  __shared__ __align__(16) char smem[55296];
  __bf16 (*Ks)[64][72] = (__bf16 (*)[64][72])(smem);            // [2][64][72]
  __bf16 (*Vs)[64][72] = (__bf16 (*)[64][72])(smem + 18432);    // [2][64][72]
  __bf16 (*Ps)[16][72] = (__bf16 (*)[16][72])(smem + 36864);    // [8][16][72]
  float (*Os)[64]      = (float (*)[64])(smem);                 // merge overlay
  float* ms = (float*)(smem + 16384);
  float* ls = (float*)(smem + 16640);

  int bh = blockIdx.y;
  int b = bh >> 4, h = bh & 15;
  int bxA = blockIdx.x;        // 0..15
  int bxB = NT - 1 - bxA;      // 31..16
  int tid = threadIdx.x;
  int lane = tid & 63, w = tid >> 6;   // w 0..7
  int wq = w & 3;                      // q-row wave slot
  int g = w >> 2;                      // KV parity group
  int l15 = lane & 15, hi = lane >> 4;
  int hi4 = hi * 4;
  size_t bT = (size_t)b * TDIM;

  // ones B-fragment: column 0 of the l-MFMA
  bf16x8 onesb;
#pragma unroll
  for (int i = 0; i < 8; ++i) onesb[i] = (l15 == 0) ? (__bf16)1.0f : (__bf16)0.0f;

  bf16x8 qfA[2], qfB[2];
  {
    const __bf16* qp = qkv + (bT + bxA * 64 + wq * 16 + l15) * QKVS + h * DHE;
    qfA[0] = *(const bf16x8*)(qp + hi * 8);
    qfA[1] = *(const bf16x8*)(qp + 32 + hi * 8);
    qp = qkv + (bT + bxB * 64 + wq * 16 + l15) * QKVS + h * DHE;
    qfB[0] = *(const bf16x8*)(qp + hi * 8);
    qfB[1] = *(const bf16x8*)(qp + 32 + hi * 8);
  }

  float mA = -INFINITY, mB = -INFINITY;   // running max (log2-scaled domain), row = l15
  f32x4 lA = (f32x4){0.f, 0.f, 0.f, 0.f}; // row sums in lanes l15==0 (rows hi*4+r)
  f32x4 lB = (f32x4){0.f, 0.f, 0.f, 0.f};
  f32x4 oA[4], oB[4];
#pragma unroll
  for (int n = 0; n < 4; ++n) {
    oA[n] = (f32x4){0.f, 0.f, 0.f, 0.f};
    oB[n] = (f32x4){0.f, 0.f, 0.f, 0.f};
  }

  int g_tid = tid & 255;
  int r0 = g_tid >> 3, c8 = (g_tid & 7) * 8;

  auto process = [&](const bf16x8* qf, float& m_i, f32x4& l_acc, f32x4* oacc,
                     int bx, int t2) {
    f32x4 sacc[4];
#pragma unroll
    for (int n = 0; n < 4; ++n) sacc[n] = (f32x4){0.f, 0.f, 0.f, 0.f};
    __builtin_amdgcn_s_setprio(1);
#pragma unroll
    for (int n = 0; n < 4; ++n)
#pragma unroll
      for (int kk = 0; kk < 2; ++kk) {
        bf16x8 kf = *(const bf16x8*)&Ks[g][n * 16 + l15][kk * 32 + hi * 8];
        sacc[n] = __builtin_amdgcn_mfma_f32_16x16x32_bf16(kf, qf[kk], sacc[n], 0, 0, 0);
      }
    __builtin_amdgcn_s_setprio(0);

    // causal mask on diag tile: tk(local)=n*16+hi4+j > tq(local)=wq*16+l15
    int myq = wq * 16 + l15;
    if (t2 == bx) {
#pragma unroll
      for (int n = 0; n < 4; ++n)
#pragma unroll
        for (int j = 0; j < 4; ++j)
          if (n * 16 + hi4 + j > myq) sacc[n][j] = -INFINITY;
    }

    // row max: 16 in-lane + 2 shfl (across hi groups)
    float mx = sacc[0][0];
#pragma unroll
    for (int n = 0; n < 4; ++n) {
      float a0 = fmaxf(sacc[n][0], sacc[n][1]);
      float a1 = fmaxf(sacc[n][2], sacc[n][3]);
      mx = fmaxf(mx, fmaxf(a0, a1));
    }
    mx = fmaxf(mx, __shfl_xor(mx, 16));
    mx = fmaxf(mx, __shfl_xor(mx, 32));
    mx *= SC2;   // log2-scaled domain

    // defer-max: rescale only if some row grew by > 8 (=> P <= 2^8)
    if (!__all(mx - m_i <= 8.0f)) {
      float nm = fmaxf(m_i, mx);
      float al = exp2f(m_i - nm);
      m_i = nm;
#pragma unroll
      for (int r = 0; r < 4; ++r) {
        float ao = __shfl(al, hi4 + r);   // alpha for O-row hi*4+r
        l_acc[r] *= ao;
#pragma unroll
        for (int n = 0; n < 4; ++n) oacc[n][r] *= ao;
      }
    }

    // p = exp2(s*SC2 - m), packed vector writes to Ps
    float negm = -m_i;
#pragma unroll
    for (int n = 0; n < 4; ++n) {
      bf16x4 pv;
#pragma unroll
      for (int j = 0; j < 4; ++j)
        pv[j] = (__bf16)exp2f(fmaf(sacc[n][j], SC2, negm));
      *(bf16x4*)&Ps[w][l15][n * 16 + hi4] = pv;
    }

    // PV + l accumulate
    bf16x8 pa0 = *(const bf16x8*)&Ps[w][l15][hi * 8];
    bf16x8 pa1 = *(const bf16x8*)&Ps[w][l15][32 + hi * 8];
    __builtin_amdgcn_s_setprio(1);
#pragma unroll
    for (int n = 0; n < 4; ++n) {
      bf16x8 vf0 = *(const bf16x8*)&Vs[g][n * 16 + l15][hi * 8];
      bf16x8 vf1 = *(const bf16x8*)&Vs[g][n * 16 + l15][32 + hi * 8];
      oacc[n] = __builtin_amdgcn_mfma_f32_16x16x32_bf16(pa0, vf0, oacc[n], 0, 0, 0);
      oacc[n] = __builtin_amdgcn_mfma_f32_16x16x32_bf16(pa1, vf1, oacc[n], 0, 0, 0);
    }
    l_acc = __builtin_amdgcn_mfma_f32_16x16x32_bf16(pa0, onesb, l_acc, 0, 0, 0);
    l_acc = __builtin_amdgcn_mfma_f32_16x16x32_bf16(pa1, onesb, l_acc, 0, 0, 0);
    __builtin_amdgcn_s_setprio(0);
  };

  for (int j = 0; j <= bxB / 2; ++j) {
    int t2 = 2 * j + g;
    bool have = (t2 <= bxB);
    __syncthreads();
    if (have) {
#pragma unroll
      for (int rr = 0; rr < 2; ++rr) {
        int row = rr * 32 + r0;
        *(bf16x8*)&Ks[g][row][c8] =
            *(const bf16x8*)(qkv + (bT + t2 * 64 + row) * QKVS + 1024 + h * DHE + c8);
        *(bf16x8*)&Vs[g][row][c8] =
            *(const bf16x8*)(vt + ((size_t)bh * 64 + row) * TDIM + t2 * 64 + c8);
      }
    }
    __syncthreads();
    if (t2 <= bxA) process(qfA, mA, lA, oA, bxA, t2);
    if (have)      process(qfB, mB, lB, oB, bxB, t2);
  }

  // epilogue: exact flash-merge of the two groups, per q-tile (log2 domain)
  auto merge = [&](int bx, float m_i, const f32x4& l_acc, f32x4* oacc) {
    float m_o[4], l_o[4];
#pragma unroll
    for (int r = 0; r < 4; ++r) {
      m_o[r] = __shfl(m_i, hi4 + r);              // row = hi*4+r
      l_o[r] = __shfl(l_acc[r], lane & 48);       // from lane l15==0, same hi
    }
    __syncthreads();
    if (g == 1) {
#pragma unroll
      for (int r = 0; r < 4; ++r) {
        int lrow = wq * 16 + hi4 + r;
        if (l15 == 0) { ms[lrow] = m_o[r]; ls[lrow] = l_o[r]; }
#pragma unroll
        for (int n = 0; n < 4; ++n)
          Os[lrow][n * 16 + l15] = oacc[n][r];
      }
    }
    __syncthreads();
    if (g == 0) {
#pragma unroll
      for (int r = 0; r < 4; ++r) {
        int lrow = wq * 16 + hi4 + r;
        float m1 = ms[lrow], l1 = ls[lrow];
        float mm = fmaxf(m_o[r], m1);
        float e0 = exp2f(m_o[r] - mm), e1 = exp2f(m1 - mm);
        float inv = 1.f / (l_o[r] * e0 + l1 * e1);
        size_t row = bT + bx * 64 + lrow;
#pragma unroll
        for (int n = 0; n < 4; ++n) {
          float v = (oacc[n][r] * e0 + Os[lrow][n * 16 + l15] * e1) * inv;
          o[row * CDIM + h * DHE + n * 16 + l15] = (__bf16)v;
        }
      }
    }
  };
  merge(bxA, mA, lA, oA);
  merge(bxB, mB, lB, oB);
}

// ---------------- launch ----------------
extern "C" void kernel_launch(void* const* d_in, const int* in_sizes, int n_in,
                              void* d_out, int out_size, void* d_ws, size_t ws_size,
                              hipStream_t stream) {
  (void)in_sizes; (void)n_in; (void)out_size; (void)ws_size;
  const float* x   = (const float*)d_in[0];
  const float* Wq  = (const float*)d_in[1];
  const float* Wk  = (const float*)d_in[2];
  const float* Wv  = (const float*)d_in[3];
  const float* Wo  = (const float*)d_in[4];
  const float* bo  = (const float*)d_in[5];
  const float* W1  = (const float*)d_in[6];
  const float* b1  = (const float*)d_in[7];
  const float* W2  = (const float*)d_in[8];
  const float* b2  = (const float*)d_in[9];
  const float* g1  = (const float*)d_in[10];
  const float* be1 = (const float*)d_in[11];
  const float* g2  = (const float*)d_in[12];
  const float* be2 = (const float*)d_in[13];
  float* out = (float*)d_out;

  char* wsb = (char*)d_ws;
  const size_t MB = 1024 * 1024;
  __bf16* Wqkvb = (__bf16*)(wsb + 0);
  __bf16* Wob   = (__bf16*)(wsb + 6  * MB);
  __bf16* W1b   = (__bf16*)(wsb + 8  * MB);
  __bf16* W2b   = (__bf16*)(wsb + 16 * MB);
  __bf16* qkvb  = (__bf16*)(wsb + 24 * MB);
  __bf16* hb    = (__bf16*)(wsb + 24 * MB);   // overlays qkvb+vt (dead by FFN)
  __bf16* vtb   = (__bf16*)(wsb + 48 * MB);
  __bf16* x1b   = (__bf16*)(wsb + 56 * MB);
  __bf16* attnb = (__bf16*)(wsb + 56 * MB);
  float*  xmid  = (float*) (wsb + 64 * MB);
  __bf16* x2b   = (__bf16*)(wsb + 80 * MB);
  float*  stats = (float*) (wsb + 88 * MB);
  float*  p0    = (float*) (wsb + 0);         // FFN2 partial 0 (over dead weights)
  float*  p1    = (float*) (wsb + 48 * MB);   // FFN2 partial 1 (over dead vt/x1b)
  float* sum1 = stats,        *sq1 = stats + 2048;
  float* sum2 = stats + 4096, *sq2 = stats + 6144;

  hipMemsetAsync(stats, 0, 4 * 2048 * sizeof(float), stream);

  // fused weight repacks (one launch)
  pack_all<<<dim3(12288), 256, 0, stream>>>(Wq, Wk, Wv, Wo, W1, W2,
                                            Wqkvb, Wob, W1b, W2b);

  // LN1 -> x1b
  ln_stats<<<dim3(CDIM / 256, BDIM, 16), 256, 0, stream>>>(x, sum1, sq1);
  ln_apply<<<dim3((BDIM * TDIM * CDIM) / 256), 256, 0, stream>>>(x, sum1, sq1, g1, be1, x1b);

  // fused QKV projection (bf16 out): 256x256 pipelined GEMM, grid 12x16=192
  gemm256<false, false, true><<<dim3(192, 1), 512, 0, stream>>>(
      x1b, Wqkvb, nullptr, qkvb, qkvb, 4096, 3072, 1024, 1024, 12);

  // V transpose for PV operand
  transp_v<<<dim3(TDIM / 32, 64), 256, 0, stream>>>(qkvb, vtb);

  // MFMA flash attention (paired q-tiles, split-KV, in-lane softmax) -> attnb
  attn_mfma<<<dim3(NT / 2, BDIM * HDIM), 512, 0, stream>>>(qkvb, vtb, attnb);

  // output projection + residual (N=1024 -> 128x128 kernel)
  gemm_bf16<true, true, false, false><<<dim3(8, 32), 256, 0, stream>>>(
      attnb, Wob, bo, x, xmid, 4096, 1024, 1024);

  // LN2 -> x2b
  ln_stats<<<dim3(CDIM / 256, BDIM, 16), 256, 0, stream>>>(xmid, sum2, sq2);
  ln_apply<<<dim3((BDIM * TDIM * CDIM) / 256), 256, 0, stream>>>(xmid, sum2, sq2, g2, be2, x2b);

  // FFN1: 256x256 pipelined GEMM, grid 16x16=256
  gemm256<true, true, true><<<dim3(256, 1), 512, 0, stream>>>(
      x2b, W1b, b1, hb, hb, 4096, 4096, 1024, 1024, 16);

  // FFN2: split-K=2 on 256x256 GEMM -> fp32 partials, then fused reduce
  gemm256<false, false, false><<<dim3(64, 2), 512, 0, stream>>>(
      hb, W2b, nullptr, p0, p1, 4096, 1024, 2048, 4096, 4);
  ffn2_reduce<<<dim3(4096), 256, 0, stream>>>(p0, p1, b2, xmid, out);
}

// Round 8
// 257.343 us; speedup vs baseline: 7.8541x; 1.0607x over previous
//
#include <hip/hip_runtime.h>
#include <math.h>

// Transformer block. bf16 MFMA GEMMs + bf16 MFMA flash attention.
// R8: gemm256 K-tile loop rebuilt barrier-minimal: per K-tile all stages
// front-loaded, full-B register tile (24 ds_read_b128/lane), ONE vmcnt(0) +
// ONE barrier. No intra-tile lockstep; fixes latent staging race.
// B=2 T=2048 C=1024 H=16 DH=64 F=4096. LN over TIME axis (ddof=1).
//
// Workspace (byte offsets):
//   [0,6M)     Wqkvb bf16 [3072][1024]  ([N][K])   } dead by FFN2 -> p0 fp32 [0,16M)
//   [6M,8M)    Wob   bf16 [1024][1024]             }
//   [8M,16M)   W1b   bf16 [4096][1024]             }
//   [16M,24M)  W2b   bf16 [1024][4096]
//   [24M,48M)  qkvb  bf16 [4096][3072]   \ overlaid by hb bf16 [4096][4096] ([24M,56M))
//   [48M,56M)  vt    bf16 [2048][2048]   /  vt dead after attn -> p1 fp32 [48M,64M)
//   [56M,64M)  x1b bf16, then attnb bf16 (dead after Wo-proj)
//   [64M,80M)  xmid fp32 [4096][1024]
//   [80M,88M)  x2b bf16
//   [88M,88M+32K) LN stats

#define TDIM 2048
#define BDIM 2
#define CDIM 1024
#define HDIM 16
#define DHE  64
#define QKVS 3072
#define NT   32          // T/64 q-tiles
#define LNEPS 1e-5f
#define SC2  0.0450842200278f   // (1/32) * log2(e)

typedef float f32x4 __attribute__((ext_vector_type(4)));
typedef __bf16 bf16x8 __attribute__((ext_vector_type(8)));
typedef __bf16 bf16x4 __attribute__((ext_vector_type(4)));

__device__ __forceinline__ void gld_lds16(const __bf16* g, __bf16* l) {
  __builtin_amdgcn_global_load_lds(
      (const __attribute__((address_space(1))) void*)g,
      (__attribute__((address_space(3))) void*)l, 16, 0, 0);
}

// ---------------- LayerNorm over T ----------------
__global__ __launch_bounds__(256) void ln_stats(const float* __restrict__ x,
                                                float* __restrict__ sumv,
                                                float* __restrict__ sqv) {
  int c = blockIdx.x * 256 + threadIdx.x;
  int b = blockIdx.y;
  int t0 = blockIdx.z * (TDIM / 16);
  const float* xp = x + ((size_t)b * TDIM + t0) * CDIM + c;
  float s = 0.f, q = 0.f;
  for (int t = 0; t < TDIM / 16; ++t) {
    float v = xp[(size_t)t * CDIM];
    s += v;
    q += v * v;
  }
  atomicAdd(&sumv[b * CDIM + c], s);
  atomicAdd(&sqv[b * CDIM + c], q);
}

__global__ __launch_bounds__(256) void ln_apply(const float* __restrict__ x,
    const float* __restrict__ sumv, const float* __restrict__ sqv,
    const float* __restrict__ gamma, const float* __restrict__ beta,
    __bf16* __restrict__ y) {
  size_t i = (size_t)blockIdx.x * 256 + threadIdx.x;
  int c = (int)(i & (CDIM - 1));
  int b = (int)(i >> 21);
  float mean = sumv[b * CDIM + c] * (1.f / TDIM);
  float var = (sqv[b * CDIM + c] - mean * mean * (float)TDIM) * (1.f / (TDIM - 1));
  float rstd = rsqrtf(var + LNEPS);
  y[i] = (__bf16)(gamma[c] * (x[i] - mean) * rstd + beta[c]);
}

// ---------------- fused weight repack (all four, one launch) ----------------
__global__ __launch_bounds__(256) void pack_all(
    const float* __restrict__ Wq, const float* __restrict__ Wk,
    const float* __restrict__ Wv, const float* __restrict__ Wo,
    const float* __restrict__ W1, const float* __restrict__ W2,
    __bf16* __restrict__ Wqkvb, __bf16* __restrict__ Wob,
    __bf16* __restrict__ W1b, __bf16* __restrict__ W2b) {
  __shared__ float tile[32][33];
  int t = blockIdx.x;
  int tx = threadIdx.x & 31, ty = threadIdx.x >> 5;
  if (t < 3072) {
    int mat = t >> 10, rem = t & 1023;
    int h = rem >> 6, rr = rem & 63;
    int c0 = (rr & 31) * 32, d0 = (rr >> 5) * 32;
    const float* W = (mat == 0) ? Wq : (mat == 1) ? Wk : Wv;
#pragma unroll
    for (int i = 0; i < 4; ++i)
      tile[ty + i * 8][tx] = W[((size_t)h * CDIM + c0 + ty + i * 8) * DHE + d0 + tx];
    __syncthreads();
#pragma unroll
    for (int i = 0; i < 4; ++i) {
      int n = mat * 1024 + h * 64 + d0 + ty + i * 8;
      Wqkvb[(size_t)n * CDIM + c0 + tx] = (__bf16)tile[tx][ty + i * 8];
    }
  } else {
    const float* in; __bf16* outp; int Cc, R, l;
    if (t < 4096)      { in = Wo; outp = Wob; R = 1024; Cc = 1024; l = t - 3072; }
    else if (t < 8192) { in = W1; outp = W1b; R = 1024; Cc = 4096; l = t - 4096; }
    else               { in = W2; outp = W2b; R = 4096; Cc = 1024; l = t - 8192; }
    int ncx = Cc >> 5;
    int c0 = (l % ncx) * 32, r0 = (l / ncx) * 32;
#pragma unroll
    for (int i = 0; i < 4; ++i)
      tile[ty + i * 8][tx] = in[(size_t)(r0 + ty + i * 8) * Cc + c0 + tx];
    __syncthreads();
#pragma unroll
    for (int i = 0; i < 4; ++i)
      outp[(size_t)(c0 + ty + i * 8) * R + r0 + tx] = (__bf16)tile[tx][ty + i * 8];
  }
}

// V part of qkvb -> vt[bh*64+d][t]
__global__ __launch_bounds__(256) void transp_v(const __bf16* __restrict__ qkv,
    __bf16* __restrict__ vtb) {
  __shared__ __bf16 tile[32][33];
  int bh = blockIdx.y >> 1, d0 = (blockIdx.y & 1) * 32;
  int b = bh >> 4, h = bh & 15;
  int t0 = blockIdx.x * 32;
  int tx = threadIdx.x & 31, ty = threadIdx.x >> 5;
#pragma unroll
  for (int i = 0; i < 4; ++i)
    tile[ty + i * 8][tx] = qkv[((size_t)b * TDIM + t0 + ty + i * 8) * QKVS + 2048 + h * DHE + d0 + tx];
  __syncthreads();
#pragma unroll
  for (int i = 0; i < 4; ++i)
    vtb[((size_t)bh * 64 + d0 + ty + i * 8) * TDIM + t0 + tx] = tile[tx][ty + i * 8];
}

// ---------------- 128x128 bf16 MFMA GEMM (kept for Wo projection) ----------------
template<bool BIAS, bool RES, bool RELU, bool OUTBF>
__global__ __launch_bounds__(256) void gemm_bf16(
    const __bf16* __restrict__ Ag, const __bf16* __restrict__ Bg,
    const float* __restrict__ bias, const float* __restrict__ res,
    void* __restrict__ Cm, int M, int N, int K) {
  __shared__ __bf16 As[128 * 32];
  __shared__ __bf16 Bs[128 * 32];
  int tid = threadIdx.x;
  int lane = tid & 63, wid = tid >> 6;
  int wr = wid >> 1, wc = wid & 1;
  int m0 = blockIdx.y * 128, n0 = blockIdx.x * 128;
  int srow = tid >> 2, scol = (tid & 3) * 8;
  int l15 = lane & 15, k8 = (lane >> 4) * 8;

  f32x4 acc[4][4];
#pragma unroll
  for (int m = 0; m < 4; ++m)
#pragma unroll
    for (int n = 0; n < 4; ++n) acc[m][n] = (f32x4){0.f, 0.f, 0.f, 0.f};

  for (int k0 = 0; k0 < K; k0 += 32) {
    __syncthreads();
    gld_lds16(Ag + (size_t)(m0 + srow) * K + k0 + scol,       As + tid * 8);
    gld_lds16(Ag + (size_t)(m0 + 64 + srow) * K + k0 + scol,  As + 2048 + tid * 8);
    gld_lds16(Bg + (size_t)(n0 + srow) * K + k0 + scol,       Bs + tid * 8);
    gld_lds16(Bg + (size_t)(n0 + 64 + srow) * K + k0 + scol,  Bs + 2048 + tid * 8);
    __syncthreads();

    bf16x8 af[4], bf[4];
#pragma unroll
    for (int m = 0; m < 4; ++m)
      af[m] = *(const bf16x8*)(As + (wr * 64 + m * 16 + l15) * 32 + k8);
#pragma unroll
    for (int n = 0; n < 4; ++n)
      bf[n] = *(const bf16x8*)(Bs + (wc * 64 + n * 16 + l15) * 32 + k8);
#pragma unroll
    for (int m = 0; m < 4; ++m)
#pragma unroll
      for (int n = 0; n < 4; ++n)
        acc[m][n] = __builtin_amdgcn_mfma_f32_16x16x32_bf16(af[m], bf[n], acc[m][n], 0, 0, 0);
  }

  int rbase = (lane >> 4) * 4;
#pragma unroll
  for (int m = 0; m < 4; ++m) {
    int row = m0 + wr * 64 + m * 16 + rbase;
#pragma unroll
    for (int n = 0; n < 4; ++n) {
      int col = n0 + wc * 64 + n * 16 + l15;
#pragma unroll
      for (int j = 0; j < 4; ++j) {
        float v = acc[m][n][j];
        size_t off = (size_t)(row + j) * N + col;
        if (BIAS) v += bias[col];
        if (RES)  v += res[off];
        if (RELU) v = fmaxf(v, 0.f);
        if (OUTBF) ((__bf16*)Cm)[off] = (__bf16)v;
        else       ((float*)Cm)[off] = v;
      }
    }
  }
}

// ---------------- 256x256 8-wave GEMM, barrier-minimal double buffer ----------------
// C[M,N] = A[M,K'] @ Bt[N,K']^T over K-chunk blockIdx.y (len K, stride ld).
// Per K-tile (BK=64): stage next tile (8 gload_lds, front-loaded), read B full
// + A halves (24 ds_read_b128/lane), 64 MFMA, then ONE vmcnt(0) + ONE barrier.
// Hazard proof: buf[cur] is read-only, buf[nxt] write-only within a tile; reads
// are lgkmcnt-consumed before each wave's barrier arrival, so after the
// collective barrier buf[cur] may be restaged. T1 XCD swizzle, T2 LDS swizzle
// (pre-swizzled global source), T5 setprio.
template<bool BIAS, bool RELU, bool OUTBF>
__global__ __launch_bounds__(512, 2) void gemm256(
    const __bf16* __restrict__ Ag, const __bf16* __restrict__ Bg,
    const float* __restrict__ bias, void* __restrict__ Cm, void* __restrict__ Cm2,
    int M, int N, int K, int ld, int gnx) {
  __shared__ __align__(16) char lds[131072];
  int tid = threadIdx.x;
  int lane = tid & 63, wid = tid >> 6;
  int wm = wid >> 2, wn = wid & 3;
  int l15 = lane & 15, hi = lane >> 4;

  size_t koff = (size_t)blockIdx.y * K;
  Ag += koff; Bg += koff;
  void* Cuse = blockIdx.y ? Cm2 : Cm;

  int nwg = gridDim.x;
  int q = nwg >> 3, r = nwg & 7;
  int xcd = blockIdx.x & 7, pos = blockIdx.x >> 3;
  int wgid = (xcd < r ? xcd * (q + 1) : r * (q + 1) + (xcd - r) * q) + pos;
  int m0 = (wgid / gnx) * 256, n0 = (wgid % gnx) * 256;

  int sr = tid >> 3;
  int skcol = ((tid & 7) ^ (sr & 7)) << 3;

  const int ac0 = (hi * 16) ^ ((l15 & 7) << 4);  // swizzled read col (bytes), kk=0
  const int ac1 = ac0 ^ 64;                      // kk=1

  f32x4 acc[8][4];
#pragma unroll
  for (int i = 0; i < 8; ++i)
#pragma unroll
    for (int j = 0; j < 4; ++j) acc[i][j] = (f32x4){0.f, 0.f, 0.f, 0.f};

  // stage one 128x64 half-tile (2 gload_lds per wave)
  auto stage = [&](const __bf16* __restrict__ G, int grow0, int k0, char* dst) {
#pragma unroll
    for (int c = 0; c < 2; ++c)
      gld_lds16(G + (size_t)(grow0 + c * 64 + sr) * ld + k0 + skcol,
                (__bf16*)(dst + c * 8192) + (size_t)tid * 8);
  };

  int KT = K >> 6;
  // prologue: K-tile 0 -> buf0
  stage(Ag, m0,       0, lds);
  stage(Ag, m0 + 128, 0, lds + 16384);
  stage(Bg, n0,       0, lds + 32768);
  stage(Bg, n0 + 128, 0, lds + 32768 + 16384);
  asm volatile("s_waitcnt vmcnt(0)" ::: "memory");
  __builtin_amdgcn_s_barrier();

  bf16x8 a[4][2], b[4][2];

#define LOADA(MH) do { \
    const char* Ac_ = lds + (size_t)cur * 65536; \
    int rb_ = (wm * 128 + (MH) * 64 + l15) * 128; \
    _Pragma("unroll") \
    for (int i_ = 0; i_ < 4; ++i_) { \
      a[i_][0] = *(const bf16x8*)(Ac_ + rb_ + i_ * 2048 + ac0); \
      a[i_][1] = *(const bf16x8*)(Ac_ + rb_ + i_ * 2048 + ac1); \
    } } while (0)
#define LOADBF do { \
    const char* Bc_ = lds + (size_t)cur * 65536 + 32768; \
    int rb_ = (wn * 64 + l15) * 128; \
    _Pragma("unroll") \
    for (int j_ = 0; j_ < 4; ++j_) { \
      b[j_][0] = *(const bf16x8*)(Bc_ + rb_ + j_ * 2048 + ac0); \
      b[j_][1] = *(const bf16x8*)(Bc_ + rb_ + j_ * 2048 + ac1); \
    } } while (0)
#define QUAD(MH, NH) do { \
    _Pragma("unroll") \
    for (int i_ = 0; i_ < 4; ++i_) \
    _Pragma("unroll") \
    for (int j_ = 0; j_ < 2; ++j_) { \
      acc[(MH)*4+i_][(NH)*2+j_] = __builtin_amdgcn_mfma_f32_16x16x32_bf16( \
          a[i_][0], b[(NH)*2+j_][0], acc[(MH)*4+i_][(NH)*2+j_], 0, 0, 0); \
      acc[(MH)*4+i_][(NH)*2+j_] = __builtin_amdgcn_mfma_f32_16x16x32_bf16( \
          a[i_][1], b[(NH)*2+j_][1], acc[(MH)*4+i_][(NH)*2+j_], 0, 0, 0); \
    } } while (0)

  for (int kt = 0; kt < KT; ++kt) {
    int cur = kt & 1;
    char* Lnxt = lds + (size_t)(cur ^ 1) * 65536;
    int k1 = (kt + 1) << 6;
    // front-load next tile's staging: full K-tile of lead time before vmcnt(0)
    if (kt < KT - 1) {
      stage(Ag, m0,       k1, Lnxt);
      stage(Ag, m0 + 128, k1, Lnxt + 16384);
      stage(Bg, n0,       k1, Lnxt + 32768);
      stage(Bg, n0 + 128, k1, Lnxt + 32768 + 16384);
    }
    LOADBF;
    LOADA(0);
    __builtin_amdgcn_s_setprio(1);
    QUAD(0, 0); QUAD(0, 1);
    __builtin_amdgcn_s_setprio(0);
    LOADA(1);
    __builtin_amdgcn_s_setprio(1);
    QUAD(1, 0); QUAD(1, 1);
    __builtin_amdgcn_s_setprio(0);
    asm volatile("" ::: "memory");                 // fence LDS reads above
    asm volatile("s_waitcnt vmcnt(0)" ::: "memory");
    __builtin_amdgcn_s_barrier();
  }
#undef LOADA
#undef LOADBF
#undef QUAD

  // epilogue
#pragma unroll
  for (int fm = 0; fm < 8; ++fm) {
    int row = m0 + wm * 128 + fm * 16 + hi * 4;
#pragma unroll
    for (int fn = 0; fn < 4; ++fn) {
      int col = n0 + wn * 64 + fn * 16 + l15;
#pragma unroll
      for (int j = 0; j < 4; ++j) {
        float v = acc[fm][fn][j];
        size_t off = (size_t)(row + j) * N + col;
        if (BIAS) v += bias[col];
        if (RELU) v = fmaxf(v, 0.f);
        if (OUTBF) ((__bf16*)Cuse)[off] = (__bf16)v;
        else       ((float*)Cuse)[off] = v;
      }
    }
  }
}

// ---------------- split-K reduce: out = p0 + p1 + b2 + xmid (all fp32) ----------------
__global__ __launch_bounds__(256) void ffn2_reduce(const float* __restrict__ p0,
    const float* __restrict__ p1, const float* __restrict__ b2,
    const float* __restrict__ xmid, float* __restrict__ out) {
  size_t i = ((size_t)blockIdx.x * 256 + threadIdx.x) * 4;
  int c = (int)(i & (CDIM - 1));
  float4 a = *(const float4*)(p0 + i);
  float4 b = *(const float4*)(p1 + i);
  float4 r = *(const float4*)(xmid + i);
  float4 bb = *(const float4*)(b2 + c);
  float4 v;
  v.x = a.x + b.x + r.x + bb.x;
  v.y = a.y + b.y + r.y + bb.y;
  v.z = a.z + b.z + r.z + bb.z;
  v.w = a.w + b.w + r.w + bb.w;
  *(float4*)(out + i) = v;
}

// ---------------- MFMA flash attention (swapped QK^T in-lane softmax) ----------------
__global__ __launch_bounds__(512, 4) void attn_mfma(const __bf16* __restrict__ qkv,
    const __bf16* __restrict__ vt, __bf16* __restrict__ o) {
  __shared__ __align__(16) char smem[55296];
  __bf16 (*Ks)[64][72] = (__bf16 (*)[64][72])(smem);            // [2][64][72]
  __bf16 (*Vs)[64][72] = (__bf16 (*)[64][72])(smem + 18432);    // [2][64][72]
  __bf16 (*Ps)[16][72] = (__bf16 (*)[16][72])(smem + 36864);    // [8][16][72]
  float (*Os)[64]      = (float (*)[64])(smem);                 // merge overlay
  float* ms = (float*)(smem + 16384);
  float* ls = (float*)(smem + 16640);

  int bh = blockIdx.y;
  int b = bh >> 4, h = bh & 15;
  int bxA = blockIdx.x;        // 0..15
  int bxB = NT - 1 - bxA;      // 31..16
  int tid = threadIdx.x;
  int lane = tid & 63, w = tid >> 6;   // w 0..7
  int wq = w & 3;                      // q-row wave slot
  int g = w >> 2;                      // KV parity group
  int l15 = lane & 15, hi = lane >> 4;
  int hi4 = hi * 4;
  size_t bT = (size_t)b * TDIM;

  bf16x8 onesb;
#pragma unroll
  for (int i = 0; i < 8; ++i) onesb[i] = (l15 == 0) ? (__bf16)1.0f : (__bf16)0.0f;

  bf16x8 qfA[2], qfB[2];
  {
    const __bf16* qp = qkv + (bT + bxA * 64 + wq * 16 + l15) * QKVS + h * DHE;
    qfA[0] = *(const bf16x8*)(qp + hi * 8);
    qfA[1] = *(const bf16x8*)(qp + 32 + hi * 8);
    qp = qkv + (bT + bxB * 64 + wq * 16 + l15) * QKVS + h * DHE;
    qfB[0] = *(const bf16x8*)(qp + hi * 8);
    qfB[1] = *(const bf16x8*)(qp + 32 + hi * 8);
  }

  float mA = -INFINITY, mB = -INFINITY;
  f32x4 lA = (f32x4){0.f, 0.f, 0.f, 0.f};
  f32x4 lB = (f32x4){0.f, 0.f, 0.f, 0.f};
  f32x4 oA[4], oB[4];
#pragma unroll
  for (int n = 0; n < 4; ++n) {
    oA[n] = (f32x4){0.f, 0.f, 0.f, 0.f};
    oB[n] = (f32x4){0.f, 0.f, 0.f, 0.f};
  }

  int g_tid = tid & 255;
  int r0 = g_tid >> 3, c8 = (g_tid & 7) * 8;

  auto process = [&](const bf16x8* qf, float& m_i, f32x4& l_acc, f32x4* oacc,
                     int bx, int t2) {
    f32x4 sacc[4];
#pragma unroll
    for (int n = 0; n < 4; ++n) sacc[n] = (f32x4){0.f, 0.f, 0.f, 0.f};
    __builtin_amdgcn_s_setprio(1);
#pragma unroll
    for (int n = 0; n < 4; ++n)
#pragma unroll
      for (int kk = 0; kk < 2; ++kk) {
        bf16x8 kf = *(const bf16x8*)&Ks[g][n * 16 + l15][kk * 32 + hi * 8];
        sacc[n] = __builtin_amdgcn_mfma_f32_16x16x32_bf16(kf, qf[kk], sacc[n], 0, 0, 0);
      }
    __builtin_amdgcn_s_setprio(0);

    int myq = wq * 16 + l15;
    if (t2 == bx) {
#pragma unroll
      for (int n = 0; n < 4; ++n)
#pragma unroll
        for (int j = 0; j < 4; ++j)
          if (n * 16 + hi4 + j > myq) sacc[n][j] = -INFINITY;
    }

    float mx = sacc[0][0];
#pragma unroll
    for (int n = 0; n < 4; ++n) {
      float a0 = fmaxf(sacc[n][0], sacc[n][1]);
      float a1 = fmaxf(sacc[n][2], sacc[n][3]);
      mx = fmaxf(mx, fmaxf(a0, a1));
    }
    mx = fmaxf(mx, __shfl_xor(mx, 16));
    mx = fmaxf(mx, __shfl_xor(mx, 32));
    mx *= SC2;

    if (!__all(mx - m_i <= 8.0f)) {
      float nm = fmaxf(m_i, mx);
      float al = exp2f(m_i - nm);
      m_i = nm;
#pragma unroll
      for (int r = 0; r < 4; ++r) {
        float ao = __shfl(al, hi4 + r);
        l_acc[r] *= ao;
#pragma unroll
        for (int n = 0; n < 4; ++n) oacc[n][r] *= ao;
      }
    }

    float negm = -m_i;
#pragma unroll
    for (int n = 0; n < 4; ++n) {
      bf16x4 pv;
#pragma unroll
      for (int j = 0; j < 4; ++j)
        pv[j] = (__bf16)exp2f(fmaf(sacc[n][j], SC2, negm));
      *(bf16x4*)&Ps[w][l15][n * 16 + hi4] = pv;
    }

    bf16x8 pa0 = *(const bf16x8*)&Ps[w][l15][hi * 8];
    bf16x8 pa1 = *(const bf16x8*)&Ps[w][l15][32 + hi * 8];
    __builtin_amdgcn_s_setprio(1);
#pragma unroll
    for (int n = 0; n < 4; ++n) {
      bf16x8 vf0 = *(const bf16x8*)&Vs[g][n * 16 + l15][hi * 8];
      bf16x8 vf1 = *(const bf16x8*)&Vs[g][n * 16 + l15][32 + hi * 8];
      oacc[n] = __builtin_amdgcn_mfma_f32_16x16x32_bf16(pa0, vf0, oacc[n], 0, 0, 0);
      oacc[n] = __builtin_amdgcn_mfma_f32_16x16x32_bf16(pa1, vf1, oacc[n], 0, 0, 0);
    }
    l_acc = __builtin_amdgcn_mfma_f32_16x16x32_bf16(pa0, onesb, l_acc, 0, 0, 0);
    l_acc = __builtin_amdgcn_mfma_f32_16x16x32_bf16(pa1, onesb, l_acc, 0, 0, 0);
    __builtin_amdgcn_s_setprio(0);
  };

  for (int j = 0; j <= bxB / 2; ++j) {
    int t2 = 2 * j + g;
    bool have = (t2 <= bxB);
    __syncthreads();
    if (have) {
#pragma unroll
      for (int rr = 0; rr < 2; ++rr) {
        int row = rr * 32 + r0;
        *(bf16x8*)&Ks[g][row][c8] =
            *(const bf16x8*)(qkv + (bT + t2 * 64 + row) * QKVS + 1024 + h * DHE + c8);
        *(bf16x8*)&Vs[g][row][c8] =
            *(const bf16x8*)(vt + ((size_t)bh * 64 + row) * TDIM + t2 * 64 + c8);
      }
    }
    __syncthreads();
    if (t2 <= bxA) process(qfA, mA, lA, oA, bxA, t2);
    if (have)      process(qfB, mB, lB, oB, bxB, t2);
  }

  auto merge = [&](int bx, float m_i, const f32x4& l_acc, f32x4* oacc) {
    float m_o[4], l_o[4];
#pragma unroll
    for (int r = 0; r < 4; ++r) {
      m_o[r] = __shfl(m_i, hi4 + r);
      l_o[r] = __shfl(l_acc[r], lane & 48);
    }
    __syncthreads();
    if (g == 1) {
#pragma unroll
      for (int r = 0; r < 4; ++r) {
        int lrow = wq * 16 + hi4 + r;
        if (l15 == 0) { ms[lrow] = m_o[r]; ls[lrow] = l_o[r]; }
#pragma unroll
        for (int n = 0; n < 4; ++n)
          Os[lrow][n * 16 + l15] = oacc[n][r];
      }
    }
    __syncthreads();
    if (g == 0) {
#pragma unroll
      for (int r = 0; r < 4; ++r) {
        int lrow = wq * 16 + hi4 + r;
        float m1 = ms[lrow], l1 = ls[lrow];
        float mm = fmaxf(m_o[r], m1);
        float e0 = exp2f(m_o[r] - mm), e1 = exp2f(m1 - mm);
        float inv = 1.f / (l_o[r] * e0 + l1 * e1);
        size_t row = bT + bx * 64 + lrow;
#pragma unroll
        for (int n = 0; n < 4; ++n) {
          float v = (oacc[n][r] * e0 + Os[lrow][n * 16 + l15] * e1) * inv;
          o[row * CDIM + h * DHE + n * 16 + l15] = (__bf16)v;
        }
      }
    }
  };
  merge(bxA, mA, lA, oA);
  merge(bxB, mB, lB, oB);
}

// ---------------- launch ----------------
extern "C" void kernel_launch(void* const* d_in, const int* in_sizes, int n_in,
                              void* d_out, int out_size, void* d_ws, size_t ws_size,
                              hipStream_t stream) {
  (void)in_sizes; (void)n_in; (void)out_size; (void)ws_size;
  const float* x   = (const float*)d_in[0];
  const float* Wq  = (const float*)d_in[1];
  const float* Wk  = (const float*)d_in[2];
  const float* Wv  = (const float*)d_in[3];
  const float* Wo  = (const float*)d_in[4];
  const float* bo  = (const float*)d_in[5];
  const float* W1  = (const float*)d_in[6];
  const float* b1  = (const float*)d_in[7];
  const float* W2  = (const float*)d_in[8];
  const float* b2  = (const float*)d_in[9];
  const float* g1  = (const float*)d_in[10];
  const float* be1 = (const float*)d_in[11];
  const float* g2  = (const float*)d_in[12];
  const float* be2 = (const float*)d_in[13];
  float* out = (float*)d_out;

  char* wsb = (char*)d_ws;
  const size_t MB = 1024 * 1024;
  __bf16* Wqkvb = (__bf16*)(wsb + 0);
  __bf16* Wob   = (__bf16*)(wsb + 6  * MB);
  __bf16* W1b   = (__bf16*)(wsb + 8  * MB);
  __bf16* W2b   = (__bf16*)(wsb + 16 * MB);
  __bf16* qkvb  = (__bf16*)(wsb + 24 * MB);
  __bf16* hb    = (__bf16*)(wsb + 24 * MB);   // overlays qkvb+vt (dead by FFN)
  __bf16* vtb   = (__bf16*)(wsb + 48 * MB);
  __bf16* x1b   = (__bf16*)(wsb + 56 * MB);
  __bf16* attnb = (__bf16*)(wsb + 56 * MB);
  float*  xmid  = (float*) (wsb + 64 * MB);
  __bf16* x2b   = (__bf16*)(wsb + 80 * MB);
  float*  stats = (float*) (wsb + 88 * MB);
  float*  p0    = (float*) (wsb + 0);         // FFN2 partial 0 (over dead weights)
  float*  p1    = (float*) (wsb + 48 * MB);   // FFN2 partial 1 (over dead vt/x1b)
  float* sum1 = stats,        *sq1 = stats + 2048;
  float* sum2 = stats + 4096, *sq2 = stats + 6144;

  hipMemsetAsync(stats, 0, 4 * 2048 * sizeof(float), stream);

  pack_all<<<dim3(12288), 256, 0, stream>>>(Wq, Wk, Wv, Wo, W1, W2,
                                            Wqkvb, Wob, W1b, W2b);

  // LN1 -> x1b
  ln_stats<<<dim3(CDIM / 256, BDIM, 16), 256, 0, stream>>>(x, sum1, sq1);
  ln_apply<<<dim3((BDIM * TDIM * CDIM) / 256), 256, 0, stream>>>(x, sum1, sq1, g1, be1, x1b);

  // fused QKV projection (bf16 out): grid 12x16=192
  gemm256<false, false, true><<<dim3(192, 1), 512, 0, stream>>>(
      x1b, Wqkvb, nullptr, qkvb, qkvb, 4096, 3072, 1024, 1024, 12);

  // V transpose for PV operand
  transp_v<<<dim3(TDIM / 32, 64), 256, 0, stream>>>(qkvb, vtb);

  // MFMA flash attention -> attnb
  attn_mfma<<<dim3(NT / 2, BDIM * HDIM), 512, 0, stream>>>(qkvb, vtb, attnb);

  // output projection + residual (N=1024 -> 128x128 kernel)
  gemm_bf16<true, true, false, false><<<dim3(8, 32), 256, 0, stream>>>(
      attnb, Wob, bo, x, xmid, 4096, 1024, 1024);

  // LN2 -> x2b
  ln_stats<<<dim3(CDIM / 256, BDIM, 16), 256, 0, stream>>>(xmid, sum2, sq2);
  ln_apply<<<dim3((BDIM * TDIM * CDIM) / 256), 256, 0, stream>>>(xmid, sum2, sq2, g2, be2, x2b);

  // FFN1: grid 16x16=256
  gemm256<true, true, true><<<dim3(256, 1), 512, 0, stream>>>(
      x2b, W1b, b1, hb, hb, 4096, 4096, 1024, 1024, 16);

  // FFN2: split-K=2 -> fp32 partials, then fused reduce
  gemm256<false, false, false><<<dim3(64, 2), 512, 0, stream>>>(
      hb, W2b, nullptr, p0, p1, 4096, 1024, 2048, 4096, 4);
  ffn2_reduce<<<dim3(4096), 256, 0, stream>>>(p0, p1, b2, xmid, out);
}